// Round 18
// baseline (224.756 us; speedup 1.0000x reference)
//
#include <hip/hip_runtime.h>
#include <math.h>

#define S_LEN 4096
#define HID   2048
#define NH    16
#define HD    128
#define NKV   2048
#define KT    64
#define QBLK  256
#define NT    (NKV / KT)
// (1/sqrt(128)) * log2(e) -- folded into Q so QK^T lands in exp2 domain
#define QSCALE 0.12754103668587426f

typedef __attribute__((ext_vector_type(8))) _Float16 half8;
typedef __attribute__((ext_vector_type(4))) _Float16 half4;
typedef __attribute__((ext_vector_type(2))) __fp16 fp16x2;
typedef __attribute__((ext_vector_type(4))) float f32x4;
typedef __attribute__((ext_vector_type(16))) float f32x16;

#define GLB_AS __attribute__((address_space(1)))
#define LDS_AS __attribute__((address_space(3)))

#if __has_builtin(__builtin_amdgcn_exp2f)
#define EXP2(x) __builtin_amdgcn_exp2f(x)
#else
#define EXP2(x) exp2f(x)
#endif

__device__ __forceinline__ void gload16(const void* g, void* l) {
  __builtin_amdgcn_global_load_lds((GLB_AS const void*)g, (LDS_AS void*)l, 16, 0, 0);
}

__device__ __forceinline__ unsigned pkrtz(float a, float b) {
  union { fp16x2 h; unsigned u; } cv;
  cv.h = __builtin_amdgcn_cvt_pkrtz(a, b);
  return cv.u;
}

// ---------- index build ----------
__global__ void k_build_idx(const int* __restrict__ hmap, int* __restrict__ gidx) {
  int i = blockIdx.x * 256 + threadIdx.x;
  if (i < NKV) gidx[i] = hmap[2 * i];
}

// ---------- fused fp32 -> fp16 conversion for x, w_qkv, w_out ----------
#define NX8  (S_LEN * HID / 8)
#define NW8  (3 * HID * HID / 8)
#define NO8  (HID * HID / 8)
__global__ void k_cvt_all(const float* __restrict__ x, const float* __restrict__ wq,
                          const float* __restrict__ wo, _Float16* __restrict__ x16,
                          _Float16* __restrict__ wq16, _Float16* __restrict__ wo16) {
  int i = blockIdx.x * 256 + threadIdx.x;
  const float* src; _Float16* dst; int j;
  if (i < NX8)            { src = x;  dst = x16;  j = i; }
  else if (i < NX8 + NW8) { src = wq; dst = wq16; j = i - NX8; }
  else                    { src = wo; dst = wo16; j = i - NX8 - NW8; }
  float4 a = ((const float4*)src)[2 * j];
  float4 b = ((const float4*)src)[2 * j + 1];
  half8 h;
  h[0] = (_Float16)a.x; h[1] = (_Float16)a.y; h[2] = (_Float16)a.z; h[3] = (_Float16)a.w;
  h[4] = (_Float16)b.x; h[5] = (_Float16)b.y; h[6] = (_Float16)b.z; h[7] = (_Float16)b.w;
  ((half8*)dst)[j] = h;
}

// ---------- 256x256 8-phase fused Q+KV GEMM (unchanged from R17) ----------
__global__ __launch_bounds__(512, 2)
void k_gemm_qkv8(const _Float16* __restrict__ A, const _Float16* __restrict__ wqkv,
                 _Float16* __restrict__ q16, const int* __restrict__ gidx,
                 char* __restrict__ kimg, char* __restrict__ vtimg)
{
  extern __shared__ __align__(16) char lds[];
  const int tid = threadIdx.x;
  const int w = tid >> 6, lane = tid & 63;
  const int l15 = lane & 15, l4 = lane >> 4;
  const int wr = w >> 2, wc = w & 3;
  const int K = HID;

  const int bid = (blockIdx.x & 7) * 32 + (blockIdx.x >> 3);  // XCD-chunked bijective
  const bool qpart = bid < 128;
  int m0, n0;
  const _Float16* B;
  if (qpart) { int b = bid;       m0 = (b >> 3) * 256; n0 = (b & 7) * 256;  B = wqkv; }
  else       { int b = bid - 128; m0 = (b >> 4) * 256; n0 = (b & 15) * 256; B = wqkv + (size_t)HID * HID; }

  const int r8 = lane >> 3;
  const int sl = (lane & 7) ^ r8;
  const _Float16* ApA[2][2];
  const _Float16* BpB[2][2];
#pragma unroll
  for (int mh = 0; mh < 2; ++mh)
#pragma unroll
    for (int L = 0; L < 2; ++L) {
      int rel = L * 128 + mh * 64 + w * 8 + r8;
      int grow = qpart ? (m0 + rel) : gidx[m0 + rel];
      ApA[mh][L] = A + (size_t)grow * K + sl * 8;
    }
#pragma unroll
  for (int nh = 0; nh < 2; ++nh)
#pragma unroll
    for (int L = 0; L < 2; ++L) {
      int row = n0 + (L * 2 + (w >> 2)) * 64 + nh * 32 + (w & 3) * 8 + r8;
      BpB[nh][L] = B + (size_t)row * K + sl * 8;
    }

  const int sw0 = (l4 ^ (l15 & 7)) * 16;
  const int sw1 = ((4 + l4) ^ (l15 & 7)) * 16;
  const int rofs = l15 * 128;

  f32x4 acc[8][4];
#pragma unroll
  for (int i = 0; i < 8; ++i)
#pragma unroll
    for (int j = 0; j < 4; ++j) acc[i][j] = (f32x4){0.f, 0.f, 0.f, 0.f};
  half8 af[4][2], bf[2][2];

#define STG_A(MH, BUF, T)                                                       \
  do {                                                                          \
    gload16(ApA[MH][0] + (T) * 64, lds + (BUF)*65536 + (MH)*16384 + w * 1024);  \
    gload16(ApA[MH][1] + (T) * 64, lds + (BUF)*65536 + (MH)*16384 + 8192 + w * 1024); \
  } while (0)
#define STG_B(NH, BUF, T)                                                       \
  do {                                                                          \
    gload16(BpB[NH][0] + (T) * 64, lds + (BUF)*65536 + 32768 + (NH)*16384 + w * 1024); \
    gload16(BpB[NH][1] + (T) * 64, lds + (BUF)*65536 + 32768 + (NH)*16384 + 8192 + w * 1024); \
  } while (0)

#define PH(BUF, MH, NH, LA, LB, STG, WAITS)                                     \
  do {                                                                          \
    if (LA) {                                                                   \
      _Pragma("unroll")                                                         \
      for (int j = 0; j < 4; ++j) {                                             \
        af[j][0] = *(const half8*)(lds + (BUF)*65536 + (MH)*16384 + wr * 8192 + j * 2048 + rofs + sw0); \
        af[j][1] = *(const half8*)(lds + (BUF)*65536 + (MH)*16384 + wr * 8192 + j * 2048 + rofs + sw1); \
      }                                                                         \
    }                                                                           \
    if (LB) {                                                                   \
      _Pragma("unroll")                                                         \
      for (int jn = 0; jn < 2; ++jn) {                                          \
        bf[jn][0] = *(const half8*)(lds + (BUF)*65536 + 32768 + (NH)*16384 + wc * 4096 + jn * 2048 + rofs + sw0); \
        bf[jn][1] = *(const half8*)(lds + (BUF)*65536 + 32768 + (NH)*16384 + wc * 4096 + jn * 2048 + rofs + sw1); \
      }                                                                         \
    }                                                                           \
    STG;                                                                        \
    __builtin_amdgcn_s_barrier();                                               \
    __builtin_amdgcn_s_setprio(1);                                              \
    _Pragma("unroll")                                                           \
    for (int j = 0; j < 4; ++j)                                                 \
      _Pragma("unroll")                                                         \
      for (int jn = 0; jn < 2; ++jn)                                            \
        _Pragma("unroll")                                                       \
        for (int ks = 0; ks < 2; ++ks)                                          \
          acc[(MH)*4 + j][(NH)*2 + jn] = __builtin_amdgcn_mfma_f32_16x16x32_f16( \
              af[j][ks], bf[jn][ks], acc[(MH)*4 + j][(NH)*2 + jn], 0, 0, 0);    \
    __builtin_amdgcn_s_setprio(0);                                              \
    WAITS;                                                                      \
    __builtin_amdgcn_s_barrier();                                               \
  } while (0)

  STG_A(0, 0, 0); STG_B(1, 0, 0); STG_A(1, 0, 0); STG_B(0, 0, 0);
  STG_A(0, 1, 1); STG_B(1, 1, 1);
  asm volatile("s_waitcnt vmcnt(4)");
  __builtin_amdgcn_s_barrier();

  for (int i = 0; i < 15; ++i) {
    const int T1 = 2 * i + 1, T2 = 2 * i + 2, T3 = 2 * i + 3;
    PH(0, 0, 0, 1, 1, STG_A(1, 1, T1), (void)0);
    PH(0, 0, 1, 0, 1, STG_B(0, 1, T1), (void)0);
    PH(0, 1, 1, 1, 0, STG_A(0, 0, T2), (void)0);
    PH(0, 1, 0, 0, 1, STG_B(1, 0, T2), asm volatile("s_waitcnt vmcnt(4)"));
    PH(1, 0, 0, 1, 1, STG_A(1, 0, T2), (void)0);
    PH(1, 0, 1, 0, 1, STG_B(0, 0, T2), (void)0);
    PH(1, 1, 1, 1, 0, STG_A(0, 1, T3), (void)0);
    PH(1, 1, 0, 0, 1, STG_B(1, 1, T3), asm volatile("s_waitcnt vmcnt(4)"));
  }
  PH(0, 0, 0, 1, 1, STG_A(1, 1, 31), (void)0);
  PH(0, 0, 1, 0, 1, STG_B(0, 1, 31), (void)0);
  PH(0, 1, 1, 1, 0, (void)0, (void)0);
  PH(0, 1, 0, 0, 1, (void)0, asm volatile("s_waitcnt vmcnt(0)"));
  PH(1, 0, 0, 1, 1, (void)0, (void)0);
  PH(1, 0, 1, 0, 1, (void)0, (void)0);
  PH(1, 1, 1, 1, 0, (void)0, (void)0);
  PH(1, 1, 0, 0, 1, (void)0, (void)0);
#undef PH
#undef STG_A
#undef STG_B

#pragma unroll
  for (int mf = 0; mf < 8; ++mf)
#pragma unroll
    for (int nf = 0; nf < 4; ++nf)
#pragma unroll
      for (int e = 0; e < 4; ++e) {
        int row = m0 + wr * 128 + mf * 16 + l4 * 4 + e;
        int col = n0 + wc * 64 + nf * 16 + l15;
        _Float16 val = (_Float16)acc[mf][nf][e];
        if (qpart) {
          q16[(size_t)row * HID + col] = val;
        } else {
          int r = row;
          int t = r >> 6, j = r & 63;
          if (col < HID) {
            int h = col >> 7, d = col & 127;
            int off = (h * 32 + t) * 16384 + ((j * 256 + 2 * d) ^ ((j & 7) << 4));
            *(_Float16*)(kimg + off) = val;
          } else {
            int nn = col - HID;
            int h = nn >> 7, d = nn & 127;
            int off = (h * 32 + t) * 16384 + ((d * 128 + 2 * j) ^ ((d & 7) << 4));
            *(_Float16*)(vtimg + off) = val;
          }
        }
      }
}

// ---------- out GEMM (f32 C), 128^2 structure ----------
__global__ __launch_bounds__(256)
void k_gemm_out(const _Float16* __restrict__ A, const _Float16* __restrict__ B,
                float* __restrict__ C, int M, int N, int K)
{
  __shared__ __align__(16) char Asl[16384];
  __shared__ __align__(16) char Bsl[16384];
  const int tid = threadIdx.x;
  const int w = tid >> 6, lane = tid & 63;
  const int l15 = lane & 15, l4 = lane >> 4;
  const int m0 = blockIdx.y * 128, n0 = blockIdx.x * 128;
  const int wr = w >> 1, wc = w & 1;

  const int srow  = lane >> 3;
  const int kso   = ((lane & 7) ^ srow) * 8;
  const _Float16* Ap[4];
  const _Float16* Bp[4];
#pragma unroll
  for (int q = 0; q < 4; ++q) {
    int row = m0 + 32 * w + 8 * q + srow;
    Ap[q] = A + (size_t)row * K + kso;
    Bp[q] = B + (size_t)(n0 + 32 * w + 8 * q + srow) * K + kso;
  }

  f32x4 acc[4][4];
#pragma unroll
  for (int i = 0; i < 4; ++i)
#pragma unroll
    for (int j = 0; j < 4; ++j) acc[i][j] = (f32x4){0.f, 0.f, 0.f, 0.f};

#define STAGE_T(k0)                                                  \
  do {                                                               \
    _Pragma("unroll")                                                \
    for (int q = 0; q < 4; ++q) {                                    \
      gload16(Ap[q] + (k0), Asl + (4 * w + q) * 1024 + lane * 16);   \
      gload16(Bp[q] + (k0), Bsl + (4 * w + q) * 1024 + lane * 16);   \
    }                                                                \
  } while (0)

  STAGE_T(0);
  __syncthreads();

  const int nt = K >> 6;
  for (int t = 0; t < nt; ++t) {
    half8 af[4][2], bf[4][2];
#pragma unroll
    for (int mi = 0; mi < 4; ++mi) {
      int row = wr * 64 + mi * 16 + l15;
#pragma unroll
      for (int ks = 0; ks < 2; ++ks)
        af[mi][ks] = *(const half8*)(Asl + row * 128 + (((ks * 4 + l4) ^ (row & 7)) * 16));
    }
#pragma unroll
    for (int ni = 0; ni < 4; ++ni) {
      int row = wc * 64 + ni * 16 + l15;
#pragma unroll
      for (int ks = 0; ks < 2; ++ks)
        bf[ni][ks] = *(const half8*)(Bsl + row * 128 + (((ks * 4 + l4) ^ (row & 7)) * 16));
    }
    __syncthreads();
    if (t + 1 < nt) STAGE_T((t + 1) * 64);
    __builtin_amdgcn_s_setprio(1);
#pragma unroll
    for (int mi = 0; mi < 4; ++mi)
#pragma unroll
      for (int ni = 0; ni < 4; ++ni)
#pragma unroll
        for (int ks = 0; ks < 2; ++ks)
          acc[mi][ni] = __builtin_amdgcn_mfma_f32_16x16x32_f16(af[mi][ks], bf[ni][ks], acc[mi][ni], 0, 0, 0);
    __builtin_amdgcn_s_setprio(0);
    __syncthreads();
  }
#undef STAGE_T

  const int rbase = m0 + wr * 64 + l4 * 4;
  const int cbase = n0 + wc * 64 + l15;
#pragma unroll
  for (int mi = 0; mi < 4; ++mi)
#pragma unroll
    for (int ni = 0; ni < 4; ++ni)
#pragma unroll
      for (int e = 0; e < 4; ++e)
        C[(size_t)(rbase + mi * 16 + e) * N + cbase + ni * 16] = acc[mi][ni][e];
}

// ---------- 32x32 MFMA flash attention: wave-group phase stagger ----------
// 512 threads = 8 waves; waves 0-3 normal order, waves 4-7 defer the B-half's
// SM/PV to the next step (sB persists across the barrier) -> at any wall-clock,
// half the waves run MFMA while the other half run VALU. 4 LDS buffers (128KB),
// stage t+2 at step t, counted vmcnt(8), 2 raw barriers/step, 33 steps.
__global__ __launch_bounds__(512, 2)
void k_attn11(const _Float16* __restrict__ qmat, const char* __restrict__ kimg,
              const char* __restrict__ vtimg, const int* __restrict__ hmap,
              _Float16* __restrict__ att)
{
  extern __shared__ __align__(16) char lds[];
  const int tid = threadIdx.x;
  const int w = tid >> 6, lane = tid & 63;
  const int l31 = lane & 31;
  const bool hi = (lane >> 5) != 0;
  const int hib = hi ? 1 : 0;
  const int wodd = (__builtin_amdgcn_readfirstlane(tid >> 6) >> 2) & 1;
  const int work = (blockIdx.x & 7) * 32 + (blockIdx.x >> 3);  // XCD-chunked, bijective
  const int h  = work >> 4;
  const int q0 = (work & 15) * QBLK;

  half8 qf[8];
  {
    const int qrow = q0 + w * 32 + l31;
    const _Float16* qb = qmat + (size_t)qrow * HID + h * HD + hib * 8;
    const _Float16 qs = (_Float16)QSCALE;
#pragma unroll
    for (int dk = 0; dk < 8; ++dk) {
      half8 v = *(const half8*)(qb + 16 * dk);
#pragma unroll
      for (int q = 0; q < 8; ++q) v[q] *= qs;
      qf[dk] = v;
    }
  }

  const int swz = (l31 & 7) << 4;
  int koff[4], voff[4];
#pragma unroll
  for (int i = 0; i < 4; ++i) {
    koff[i] = l31 * 256 + ((i * 32 + hib * 16) ^ swz);
    voff[i] = 16384 + l31 * 128 + ((i * 32 + hib * 16) ^ swz);
  }

  const char* kbase = kimg  + (size_t)h * NT * 16384;
  const char* vbase = vtimg + (size_t)h * NT * 16384;

  f32x16 acc[4];
#pragma unroll
  for (int dt = 0; dt < 4; ++dt)
#pragma unroll
    for (int r = 0; r < 16; ++r) acc[dt][r] = 0.f;
  float lsum = 0.f;
  f32x16 sB;   // persists across steps for odd wave group

#define STAGE(buf, t)                                                          \
  do {                                                                         \
    const char* ks_ = kbase + (size_t)(t) * 16384;                             \
    const char* vs_ = vbase + (size_t)(t) * 16384;                             \
    char* d_ = lds + (buf) * 32768;                                            \
    gload16(ks_ + w * 1024 + lane * 16,          d_ + w * 1024);               \
    gload16(ks_ + (8 + w) * 1024 + lane * 16,    d_ + (8 + w) * 1024);         \
    gload16(vs_ + w * 1024 + lane * 16,          d_ + 16384 + w * 1024);       \
    gload16(vs_ + (8 + w) * 1024 + lane * 16,    d_ + 16384 + (8 + w) * 1024); \
  } while (0)

#define SM_HALF(S, PPK)                                                        \
  do {                                                                         \
    float p_[16];                                                              \
    _Pragma("unroll")                                                          \
    for (int r = 0; r < 16; ++r) { p_[r] = EXP2((S)[r]); lsum += p_[r]; }      \
    _Pragma("unroll")                                                          \
    for (int rq = 0; rq < 4; ++rq)                                             \
      _Pragma("unroll")                                                        \
      for (int h2 = 0; h2 < 2; ++h2)                                           \
        PPK[rq][h2] = pkrtz(p_[4 * rq + 2 * h2], p_[4 * rq + 2 * h2 + 1]);     \
  } while (0)

#define PV_HALF(PPK, KSB, CUR)                                                 \
  do {                                                                         \
    _Pragma("unroll")                                                          \
    for (int k1 = 0; k1 < 2; ++k1) {                                           \
      unsigned send0 = hi ? PPK[2 * k1][0]     : PPK[2 * k1 + 1][0];           \
      unsigned send1 = hi ? PPK[2 * k1][1]     : PPK[2 * k1 + 1][1];           \
      unsigned recv0 = (unsigned)__shfl_xor((int)send0, 32);                   \
      unsigned recv1 = (unsigned)__shfl_xor((int)send1, 32);                   \
      unsigned self0 = hi ? PPK[2 * k1 + 1][0] : PPK[2 * k1][0];               \
      unsigned self1 = hi ? PPK[2 * k1 + 1][1] : PPK[2 * k1][1];               \
      union { unsigned u[4]; half8 hv; } pf;                                   \
      pf.u[0] = hi ? recv0 : self0;                                            \
      pf.u[1] = hi ? recv1 : self1;                                            \
      pf.u[2] = hi ? self0 : recv0;                                            \
      pf.u[3] = hi ? self1 : recv1;                                            \
      __builtin_amdgcn_s_setprio(1);                                           \
      _Pragma("unroll")                                                        \
      for (int dt = 0; dt < 4; ++dt) {                                         \
        half8 vf = *(const half8*)(lds + voff[(KSB) + k1] +                    \
                    ((CUR) * 32768 + dt * 4096));                              \
        acc[dt] = __builtin_amdgcn_mfma_f32_32x32x16_f16(vf, pf.hv, acc[dt], 0, 0, 0); \
      }                                                                        \
      __builtin_amdgcn_s_setprio(0);                                           \
    }                                                                          \
  } while (0)

#define QK_HALF(S, JT, CUR)                                                    \
  do {                                                                         \
    _Pragma("unroll")                                                          \
    for (int r = 0; r < 16; ++r) (S)[r] = 0.f;                                 \
    __builtin_amdgcn_s_setprio(1);                                             \
    _Pragma("unroll")                                                          \
    for (int dk = 0; dk < 8; ++dk) {                                           \
      half8 kf = *(const half8*)(lds + koff[dk & 3] +                          \
                  ((CUR) * 32768 + (JT) * 8192 + (dk >> 2) * 128));            \
      (S) = __builtin_amdgcn_mfma_f32_32x32x16_f16(kf, qf[dk], (S), 0, 0, 0);  \
    }                                                                          \
    __builtin_amdgcn_s_setprio(0);                                             \
  } while (0)

#define BODY_E(CUR)                                                            \
  do {                                                                         \
    f32x16 sA2, sB2;                                                           \
    unsigned PA[4][2], PB[4][2];                                               \
    QK_HALF(sA2, 0, CUR); QK_HALF(sB2, 1, CUR);                                \
    SM_HALF(sA2, PA); PV_HALF(PA, 0, CUR);                                     \
    SM_HALF(sB2, PB); PV_HALF(PB, 2, CUR);                                     \
  } while (0)

#define ODD_TAIL(CP)                                                           \
  do {                                                                         \
    unsigned PB[4][2];                                                         \
    SM_HALF(sB, PB); PV_HALF(PB, 2, CP);                                       \
  } while (0)

#define ODD_HEAD(CN)                                                           \
  do {                                                                         \
    f32x16 sA;                                                                 \
    unsigned PA[4][2];                                                         \
    QK_HALF(sA, 0, CN); SM_HALF(sA, PA); PV_HALF(PA, 0, CN);                   \
    QK_HALF(sB, 1, CN);                                                        \
  } while (0)

#define STEP(CE, CP, CN, STG, WAITS, DOE, DOPREV, DOCUR)                       \
  do {                                                                         \
    STG;                                                                       \
    WAITS;                                                                     \
    __builtin_amdgcn_s_barrier();                                              \
    if (!wodd) { if (DOE) BODY_E(CE); }                                        \
    else { if (DOPREV) ODD_TAIL(CP); if (DOCUR) ODD_HEAD(CN); }                \
    __builtin_amdgcn_s_barrier();                                              \
  } while (0)

  // prologue
  STAGE(0, 0);
  STAGE(1, 1);
  // s=0: even full tile 0; odd: A-half + QK_B of tile 0
  STEP(0, 0, 0, STAGE(2, 2), asm volatile("s_waitcnt vmcnt(8)" ::: "memory"), 1, 0, 1);
  // s=1
  STEP(1, 0, 1, STAGE(3, 3), asm volatile("s_waitcnt vmcnt(8)" ::: "memory"), 1, 1, 1);
  // s = 2..29 (7 iterations of 4); step s stages tile s+2
  for (int s = 2; s <= 26; s += 4) {
    STEP(2, 1, 2, STAGE(0, s + 2), asm volatile("s_waitcnt vmcnt(8)" ::: "memory"), 1, 1, 1);
    STEP(3, 2, 3, STAGE(1, s + 3), asm volatile("s_waitcnt vmcnt(8)" ::: "memory"), 1, 1, 1);
    STEP(0, 3, 0, STAGE(2, s + 4), asm volatile("s_waitcnt vmcnt(8)" ::: "memory"), 1, 1, 1);
    STEP(1, 0, 1, STAGE(3, s + 5), asm volatile("s_waitcnt vmcnt(8)" ::: "memory"), 1, 1, 1);
  }
  // s=30, 31, 32 (no staging; tighten waits)
  STEP(2, 1, 2, (void)0, asm volatile("s_waitcnt vmcnt(4)" ::: "memory"), 1, 1, 1);
  STEP(3, 2, 3, (void)0, asm volatile("s_waitcnt vmcnt(0)" ::: "memory"), 1, 1, 1);
  STEP(0, 3, 0, (void)0, (void)0, 0, 1, 0);
#undef STEP
#undef BODY_E
#undef ODD_TAIL
#undef ODD_HEAD
#undef QK_HALF
#undef PV_HALF
#undef SM_HALF
#undef STAGE

  float lt = lsum + __shfl_xor(lsum, 32);
  const float rl = 1.0f / lt;
  const int qrow = q0 + w * 32 + l31;
  const int srow = hmap[qrow];
  _Float16* ob = att + (size_t)srow * HID + h * HD;
#pragma unroll
  for (int dt = 0; dt < 4; ++dt)
#pragma unroll
    for (int rq = 0; rq < 4; ++rq) {
      const int d0 = dt * 32 + 8 * rq + 4 * hib;
      half4 o;
      o[0] = (_Float16)(acc[dt][4 * rq + 0] * rl);
      o[1] = (_Float16)(acc[dt][4 * rq + 1] * rl);
      o[2] = (_Float16)(acc[dt][4 * rq + 2] * rl);
      o[3] = (_Float16)(acc[dt][4 * rq + 3] * rl);
      *(half4*)(ob + d0) = o;
    }
}

extern "C" void kernel_launch(void* const* d_in, const int* in_sizes, int n_in,
                              void* d_out, int out_size, void* d_ws, size_t ws_size,
                              hipStream_t stream)
{
  const float* x     = (const float*)d_in[0];
  const float* w_qkv = (const float*)d_in[1];
  const float* w_out = (const float*)d_in[2];
  const int*   hmap  = (const int*)d_in[3];
  float* out = (float*)d_out;

  char* ws = (char*)d_ws;
  int* gidx = (int*)ws;                                          ws += 8192;
  _Float16* x16    = (_Float16*)ws;  // aliased with att16 (x16 dead after QKV GEMM)
  _Float16* att16  = (_Float16*)ws;                              ws += (size_t)S_LEN * HID * 2;
  _Float16* wqkv16 = (_Float16*)ws;                              ws += (size_t)3 * HID * HID * 2;
  _Float16* wout16 = (_Float16*)ws;                              ws += (size_t)HID * HID * 2;
  _Float16* q16    = (_Float16*)ws;                              ws += (size_t)S_LEN * HID * 2;
  char* kimg  = ws;                                              ws += (size_t)NH * NT * 16384;
  char* vtimg = ws;

  k_build_idx<<<8, 256, 0, stream>>>(hmap, gidx);
  k_cvt_all<<<(NX8 + NW8 + NO8 + 255) / 256, 256, 0, stream>>>(x, w_qkv, w_out,
                                                               x16, wqkv16, wout16);

  // fused 8-phase 256^2: Q = x @ wq^T AND KV images = x[gidx] @ wkv^T
  k_gemm_qkv8<<<256, 512, 131072, stream>>>(x16, wqkv16, q16, gidx, kimg, vtimg);

  k_attn11<<<NH * (S_LEN / QBLK), 512, 131072, stream>>>(q16, kimg, vtimg, hmap, att16);

  // out = att @ w_out^T  (4096 x 2048, fp32)
  dim3 go(HID / 128, S_LEN / 128);
  k_gemm_out<<<go, 256, 0, stream>>>(att16, wout16, out, S_LEN, HID, HID);
}

// Round 19
// 216.022 us; speedup vs baseline: 1.0404x; 1.0404x over previous
//
#include <hip/hip_runtime.h>
#include <math.h>

#define S_LEN 4096
#define HID   2048
#define NH    16
#define HD    128
#define NKV   2048
#define KT    64
#define QBLK  256
#define NT    (NKV / KT)
// (1/sqrt(128)) * log2(e) -- folded into Q so QK^T lands in exp2 domain
#define QSCALE 0.12754103668587426f

typedef __attribute__((ext_vector_type(8))) _Float16 half8;
typedef __attribute__((ext_vector_type(4))) _Float16 half4;
typedef __attribute__((ext_vector_type(2))) __fp16 fp16x2;
typedef __attribute__((ext_vector_type(4))) float f32x4;
typedef __attribute__((ext_vector_type(16))) float f32x16;

#define GLB_AS __attribute__((address_space(1)))
#define LDS_AS __attribute__((address_space(3)))

#if __has_builtin(__builtin_amdgcn_exp2f)
#define EXP2(x) __builtin_amdgcn_exp2f(x)
#else
#define EXP2(x) exp2f(x)
#endif

__device__ __forceinline__ void gload16(const void* g, void* l) {
  __builtin_amdgcn_global_load_lds((GLB_AS const void*)g, (LDS_AS void*)l, 16, 0, 0);
}

__device__ __forceinline__ unsigned pkrtz(float a, float b) {
  union { fp16x2 h; unsigned u; } cv;
  cv.h = __builtin_amdgcn_cvt_pkrtz(a, b);
  return cv.u;
}

// ---------- index build ----------
__global__ void k_build_idx(const int* __restrict__ hmap, int* __restrict__ gidx) {
  int i = blockIdx.x * 256 + threadIdx.x;
  if (i < NKV) gidx[i] = hmap[2 * i];
}

// ---------- fused fp32 -> fp16 conversion for x, w_qkv, w_out ----------
#define NX8  (S_LEN * HID / 8)
#define NW8  (3 * HID * HID / 8)
#define NO8  (HID * HID / 8)
__global__ void k_cvt_all(const float* __restrict__ x, const float* __restrict__ wq,
                          const float* __restrict__ wo, _Float16* __restrict__ x16,
                          _Float16* __restrict__ wq16, _Float16* __restrict__ wo16) {
  int i = blockIdx.x * 256 + threadIdx.x;
  const float* src; _Float16* dst; int j;
  if (i < NX8)            { src = x;  dst = x16;  j = i; }
  else if (i < NX8 + NW8) { src = wq; dst = wq16; j = i - NX8; }
  else                    { src = wo; dst = wo16; j = i - NX8 - NW8; }
  float4 a = ((const float4*)src)[2 * j];
  float4 b = ((const float4*)src)[2 * j + 1];
  half8 h;
  h[0] = (_Float16)a.x; h[1] = (_Float16)a.y; h[2] = (_Float16)a.z; h[3] = (_Float16)a.w;
  h[4] = (_Float16)b.x; h[5] = (_Float16)b.y; h[6] = (_Float16)b.z; h[7] = (_Float16)b.w;
  ((half8*)dst)[j] = h;
}

// ---------- 256x256 8-phase fused Q+KV GEMM (R17, unchanged) ----------
__global__ __launch_bounds__(512, 2)
void k_gemm_qkv8(const _Float16* __restrict__ A, const _Float16* __restrict__ wqkv,
                 _Float16* __restrict__ q16, const int* __restrict__ gidx,
                 char* __restrict__ kimg, char* __restrict__ vtimg)
{
  extern __shared__ __align__(16) char lds[];
  const int tid = threadIdx.x;
  const int w = tid >> 6, lane = tid & 63;
  const int l15 = lane & 15, l4 = lane >> 4;
  const int wr = w >> 2, wc = w & 3;
  const int K = HID;

  const int bid = (blockIdx.x & 7) * 32 + (blockIdx.x >> 3);  // XCD-chunked bijective
  const bool qpart = bid < 128;
  int m0, n0;
  const _Float16* B;
  if (qpart) { int b = bid;       m0 = (b >> 3) * 256; n0 = (b & 7) * 256;  B = wqkv; }
  else       { int b = bid - 128; m0 = (b >> 4) * 256; n0 = (b & 15) * 256; B = wqkv + (size_t)HID * HID; }

  const int r8 = lane >> 3;
  const int sl = (lane & 7) ^ r8;
  const _Float16* ApA[2][2];
  const _Float16* BpB[2][2];
#pragma unroll
  for (int mh = 0; mh < 2; ++mh)
#pragma unroll
    for (int L = 0; L < 2; ++L) {
      int rel = L * 128 + mh * 64 + w * 8 + r8;
      int grow = qpart ? (m0 + rel) : gidx[m0 + rel];
      ApA[mh][L] = A + (size_t)grow * K + sl * 8;
    }
#pragma unroll
  for (int nh = 0; nh < 2; ++nh)
#pragma unroll
    for (int L = 0; L < 2; ++L) {
      int row = n0 + (L * 2 + (w >> 2)) * 64 + nh * 32 + (w & 3) * 8 + r8;
      BpB[nh][L] = B + (size_t)row * K + sl * 8;
    }

  const int sw0 = (l4 ^ (l15 & 7)) * 16;
  const int sw1 = ((4 + l4) ^ (l15 & 7)) * 16;
  const int rofs = l15 * 128;

  f32x4 acc[8][4];
#pragma unroll
  for (int i = 0; i < 8; ++i)
#pragma unroll
    for (int j = 0; j < 4; ++j) acc[i][j] = (f32x4){0.f, 0.f, 0.f, 0.f};
  half8 af[4][2], bf[2][2];

#define STG_A(MH, BUF, T)                                                       \
  do {                                                                          \
    gload16(ApA[MH][0] + (T) * 64, lds + (BUF)*65536 + (MH)*16384 + w * 1024);  \
    gload16(ApA[MH][1] + (T) * 64, lds + (BUF)*65536 + (MH)*16384 + 8192 + w * 1024); \
  } while (0)
#define STG_B(NH, BUF, T)                                                       \
  do {                                                                          \
    gload16(BpB[NH][0] + (T) * 64, lds + (BUF)*65536 + 32768 + (NH)*16384 + w * 1024); \
    gload16(BpB[NH][1] + (T) * 64, lds + (BUF)*65536 + 32768 + (NH)*16384 + 8192 + w * 1024); \
  } while (0)

#define PH(BUF, MH, NH, LA, LB, STG, WAITS)                                     \
  do {                                                                          \
    if (LA) {                                                                   \
      _Pragma("unroll")                                                         \
      for (int j = 0; j < 4; ++j) {                                             \
        af[j][0] = *(const half8*)(lds + (BUF)*65536 + (MH)*16384 + wr * 8192 + j * 2048 + rofs + sw0); \
        af[j][1] = *(const half8*)(lds + (BUF)*65536 + (MH)*16384 + wr * 8192 + j * 2048 + rofs + sw1); \
      }                                                                         \
    }                                                                           \
    if (LB) {                                                                   \
      _Pragma("unroll")                                                         \
      for (int jn = 0; jn < 2; ++jn) {                                          \
        bf[jn][0] = *(const half8*)(lds + (BUF)*65536 + 32768 + (NH)*16384 + wc * 4096 + jn * 2048 + rofs + sw0); \
        bf[jn][1] = *(const half8*)(lds + (BUF)*65536 + 32768 + (NH)*16384 + wc * 4096 + jn * 2048 + rofs + sw1); \
      }                                                                         \
    }                                                                           \
    STG;                                                                        \
    __builtin_amdgcn_s_barrier();                                               \
    __builtin_amdgcn_s_setprio(1);                                              \
    _Pragma("unroll")                                                           \
    for (int j = 0; j < 4; ++j)                                                 \
      _Pragma("unroll")                                                         \
      for (int jn = 0; jn < 2; ++jn)                                            \
        _Pragma("unroll")                                                       \
        for (int ks = 0; ks < 2; ++ks)                                          \
          acc[(MH)*4 + j][(NH)*2 + jn] = __builtin_amdgcn_mfma_f32_16x16x32_f16( \
              af[j][ks], bf[jn][ks], acc[(MH)*4 + j][(NH)*2 + jn], 0, 0, 0);    \
    __builtin_amdgcn_s_setprio(0);                                              \
    WAITS;                                                                      \
    __builtin_amdgcn_s_barrier();                                               \
  } while (0)

  STG_A(0, 0, 0); STG_B(1, 0, 0); STG_A(1, 0, 0); STG_B(0, 0, 0);
  STG_A(0, 1, 1); STG_B(1, 1, 1);
  asm volatile("s_waitcnt vmcnt(4)");
  __builtin_amdgcn_s_barrier();

  for (int i = 0; i < 15; ++i) {
    const int T1 = 2 * i + 1, T2 = 2 * i + 2, T3 = 2 * i + 3;
    PH(0, 0, 0, 1, 1, STG_A(1, 1, T1), (void)0);
    PH(0, 0, 1, 0, 1, STG_B(0, 1, T1), (void)0);
    PH(0, 1, 1, 1, 0, STG_A(0, 0, T2), (void)0);
    PH(0, 1, 0, 0, 1, STG_B(1, 0, T2), asm volatile("s_waitcnt vmcnt(4)"));
    PH(1, 0, 0, 1, 1, STG_A(1, 0, T2), (void)0);
    PH(1, 0, 1, 0, 1, STG_B(0, 0, T2), (void)0);
    PH(1, 1, 1, 1, 0, STG_A(0, 1, T3), (void)0);
    PH(1, 1, 0, 0, 1, STG_B(1, 1, T3), asm volatile("s_waitcnt vmcnt(4)"));
  }
  PH(0, 0, 0, 1, 1, STG_A(1, 1, 31), (void)0);
  PH(0, 0, 1, 0, 1, STG_B(0, 1, 31), (void)0);
  PH(0, 1, 1, 1, 0, (void)0, (void)0);
  PH(0, 1, 0, 0, 1, (void)0, asm volatile("s_waitcnt vmcnt(0)"));
  PH(1, 0, 0, 1, 1, (void)0, (void)0);
  PH(1, 0, 1, 0, 1, (void)0, (void)0);
  PH(1, 1, 1, 1, 0, (void)0, (void)0);
  PH(1, 1, 0, 0, 1, (void)0, (void)0);
#undef PH
#undef STG_A
#undef STG_B

#pragma unroll
  for (int mf = 0; mf < 8; ++mf)
#pragma unroll
    for (int nf = 0; nf < 4; ++nf)
#pragma unroll
      for (int e = 0; e < 4; ++e) {
        int row = m0 + wr * 128 + mf * 16 + l4 * 4 + e;
        int col = n0 + wc * 64 + nf * 16 + l15;
        _Float16 val = (_Float16)acc[mf][nf][e];
        if (qpart) {
          q16[(size_t)row * HID + col] = val;
        } else {
          int r = row;
          int t = r >> 6, j = r & 63;
          if (col < HID) {
            int h = col >> 7, d = col & 127;
            int off = (h * 32 + t) * 16384 + ((j * 256 + 2 * d) ^ ((j & 7) << 4));
            *(_Float16*)(kimg + off) = val;
          } else {
            int nn = col - HID;
            int h = nn >> 7, d = nn & 127;
            int off = (h * 32 + t) * 16384 + ((d * 128 + 2 * j) ^ ((d & 7) << 4));
            *(_Float16*)(vtimg + off) = val;
          }
        }
      }
}

// ---------- out GEMM (f32 C), 128^2 structure ----------
__global__ __launch_bounds__(256)
void k_gemm_out(const _Float16* __restrict__ A, const _Float16* __restrict__ B,
                float* __restrict__ C, int M, int N, int K)
{
  __shared__ __align__(16) char Asl[16384];
  __shared__ __align__(16) char Bsl[16384];
  const int tid = threadIdx.x;
  const int w = tid >> 6, lane = tid & 63;
  const int l15 = lane & 15, l4 = lane >> 4;
  const int m0 = blockIdx.y * 128, n0 = blockIdx.x * 128;
  const int wr = w >> 1, wc = w & 1;

  const int srow  = lane >> 3;
  const int kso   = ((lane & 7) ^ srow) * 8;
  const _Float16* Ap[4];
  const _Float16* Bp[4];
#pragma unroll
  for (int q = 0; q < 4; ++q) {
    int row = m0 + 32 * w + 8 * q + srow;
    Ap[q] = A + (size_t)row * K + kso;
    Bp[q] = B + (size_t)(n0 + 32 * w + 8 * q + srow) * K + kso;
  }

  f32x4 acc[4][4];
#pragma unroll
  for (int i = 0; i < 4; ++i)
#pragma unroll
    for (int j = 0; j < 4; ++j) acc[i][j] = (f32x4){0.f, 0.f, 0.f, 0.f};

#define STAGE_T(k0)                                                  \
  do {                                                               \
    _Pragma("unroll")                                                \
    for (int q = 0; q < 4; ++q) {                                    \
      gload16(Ap[q] + (k0), Asl + (4 * w + q) * 1024 + lane * 16);   \
      gload16(Bp[q] + (k0), Bsl + (4 * w + q) * 1024 + lane * 16);   \
    }                                                                \
  } while (0)

  STAGE_T(0);
  __syncthreads();

  const int nt = K >> 6;
  for (int t = 0; t < nt; ++t) {
    half8 af[4][2], bf[4][2];
#pragma unroll
    for (int mi = 0; mi < 4; ++mi) {
      int row = wr * 64 + mi * 16 + l15;
#pragma unroll
      for (int ks = 0; ks < 2; ++ks)
        af[mi][ks] = *(const half8*)(Asl + row * 128 + (((ks * 4 + l4) ^ (row & 7)) * 16));
    }
#pragma unroll
    for (int ni = 0; ni < 4; ++ni) {
      int row = wc * 64 + ni * 16 + l15;
#pragma unroll
      for (int ks = 0; ks < 2; ++ks)
        bf[ni][ks] = *(const half8*)(Bsl + row * 128 + (((ks * 4 + l4) ^ (row & 7)) * 16));
    }
    __syncthreads();
    if (t + 1 < nt) STAGE_T((t + 1) * 64);
    __builtin_amdgcn_s_setprio(1);
#pragma unroll
    for (int mi = 0; mi < 4; ++mi)
#pragma unroll
      for (int ni = 0; ni < 4; ++ni)
#pragma unroll
        for (int ks = 0; ks < 2; ++ks)
          acc[mi][ni] = __builtin_amdgcn_mfma_f32_16x16x32_f16(af[mi][ks], bf[ni][ks], acc[mi][ni], 0, 0, 0);
    __builtin_amdgcn_s_setprio(0);
    __syncthreads();
  }
#undef STAGE_T

  const int rbase = m0 + wr * 64 + l4 * 4;
  const int cbase = n0 + wc * 64 + l15;
#pragma unroll
  for (int mi = 0; mi < 4; ++mi)
#pragma unroll
    for (int ni = 0; ni < 4; ++ni)
#pragma unroll
      for (int e = 0; e < 4; ++e)
        C[(size_t)(rbase + mi * 16 + e) * N + cbase + ni * 16] = acc[mi][ni][e];
}

// ---------- 32x32 MFMA flash attention: half-tile pipeline + chain splits ----------
// R14/R17 structure; QK split into two 4-deep independent MFMA chains (merged
// with one f32x16 add); lsum accumulated via 4 partials (tree combine) to break
// the 16-deep serial FP add chain. grid 256 (1/CU), LDS 64KB.
__global__ __launch_bounds__(512, 2)
void k_attn12(const _Float16* __restrict__ qmat, const char* __restrict__ kimg,
              const char* __restrict__ vtimg, const int* __restrict__ hmap,
              _Float16* __restrict__ att)
{
  extern __shared__ __align__(16) char lds[];
  const int tid = threadIdx.x;
  const int w = tid >> 6, lane = tid & 63;
  const int l31 = lane & 31;
  const bool hi = (lane >> 5) != 0;
  const int hib = hi ? 1 : 0;
  const int work = (blockIdx.x & 7) * 32 + (blockIdx.x >> 3);  // XCD-chunked, bijective
  const int h  = work >> 4;
  const int q0 = (work & 15) * QBLK;

  half8 qf[8];
  {
    const int qrow = q0 + w * 32 + l31;
    const _Float16* qb = qmat + (size_t)qrow * HID + h * HD + hib * 8;
    const _Float16 qs = (_Float16)QSCALE;
#pragma unroll
    for (int dk = 0; dk < 8; ++dk) {
      half8 v = *(const half8*)(qb + 16 * dk);
#pragma unroll
      for (int q = 0; q < 8; ++q) v[q] *= qs;
      qf[dk] = v;
    }
  }

  const int swz = (l31 & 7) << 4;
  int koff[4], voff[4];
#pragma unroll
  for (int i = 0; i < 4; ++i) {
    koff[i] = l31 * 256 + ((i * 32 + hib * 16) ^ swz);
    voff[i] = 16384 + l31 * 128 + ((i * 32 + hib * 16) ^ swz);
  }

  const char* kbase = kimg  + (size_t)h * NT * 16384;
  const char* vbase = vtimg + (size_t)h * NT * 16384;

  f32x16 acc[4];
#pragma unroll
  for (int dt = 0; dt < 4; ++dt)
#pragma unroll
    for (int r = 0; r < 16; ++r) acc[dt][r] = 0.f;
  float lsum = 0.f;

#define STAGE(buf, t)                                                          \
  do {                                                                         \
    const char* ks_ = kbase + (size_t)(t) * 16384;                             \
    const char* vs_ = vbase + (size_t)(t) * 16384;                             \
    char* d_ = lds + (buf) * 32768;                                            \
    gload16(ks_ + w * 1024 + lane * 16,          d_ + w * 1024);               \
    gload16(ks_ + (8 + w) * 1024 + lane * 16,    d_ + (8 + w) * 1024);         \
    gload16(vs_ + w * 1024 + lane * 16,          d_ + 16384 + w * 1024);       \
    gload16(vs_ + (8 + w) * 1024 + lane * 16,    d_ + 16384 + (8 + w) * 1024); \
  } while (0)

#define SM_HALF(S, PPK)                                                        \
  do {                                                                         \
    float p_[16];                                                              \
    float ps0 = 0.f, ps1 = 0.f, ps2 = 0.f, ps3 = 0.f;                          \
    _Pragma("unroll")                                                          \
    for (int r = 0; r < 16; ++r) p_[r] = EXP2((S)[r]);                         \
    _Pragma("unroll")                                                          \
    for (int r = 0; r < 4; ++r) {                                              \
      ps0 += p_[4 * r + 0]; ps1 += p_[4 * r + 1];                              \
      ps2 += p_[4 * r + 2]; ps3 += p_[4 * r + 3];                              \
    }                                                                          \
    lsum += (ps0 + ps1) + (ps2 + ps3);                                         \
    _Pragma("unroll")                                                          \
    for (int rq = 0; rq < 4; ++rq)                                             \
      _Pragma("unroll")                                                        \
      for (int h2 = 0; h2 < 2; ++h2)                                           \
        PPK[rq][h2] = pkrtz(p_[4 * rq + 2 * h2], p_[4 * rq + 2 * h2 + 1]);     \
  } while (0)

#define PV_HALF(PPK, KSB, CUR)                                                 \
  do {                                                                         \
    _Pragma("unroll")                                                          \
    for (int k1 = 0; k1 < 2; ++k1) {                                           \
      unsigned send0 = hi ? PPK[2 * k1][0]     : PPK[2 * k1 + 1][0];           \
      unsigned send1 = hi ? PPK[2 * k1][1]     : PPK[2 * k1 + 1][1];           \
      unsigned recv0 = (unsigned)__shfl_xor((int)send0, 32);                   \
      unsigned recv1 = (unsigned)__shfl_xor((int)send1, 32);                   \
      unsigned self0 = hi ? PPK[2 * k1 + 1][0] : PPK[2 * k1][0];               \
      unsigned self1 = hi ? PPK[2 * k1 + 1][1] : PPK[2 * k1][1];               \
      union { unsigned u[4]; half8 hv; } pf;                                   \
      pf.u[0] = hi ? recv0 : self0;                                            \
      pf.u[1] = hi ? recv1 : self1;                                            \
      pf.u[2] = hi ? self0 : recv0;                                            \
      pf.u[3] = hi ? self1 : recv1;                                            \
      __builtin_amdgcn_s_setprio(1);                                           \
      _Pragma("unroll")                                                        \
      for (int dt = 0; dt < 4; ++dt) {                                         \
        half8 vf = *(const half8*)(lds + voff[(KSB) + k1] +                    \
                    ((CUR) * 32768 + dt * 4096));                              \
        acc[dt] = __builtin_amdgcn_mfma_f32_32x32x16_f16(vf, pf.hv, acc[dt], 0, 0, 0); \
      }                                                                        \
      __builtin_amdgcn_s_setprio(0);                                           \
    }                                                                          \
  } while (0)

// QK of one half as TWO independent 4-deep chains, merged with one vector add.
#define QK_HALF(S, JT, CUR)                                                    \
  do {                                                                         \
    f32x16 s0_, s1_;                                                           \
    _Pragma("unroll")                                                          \
    for (int r = 0; r < 16; ++r) { s0_[r] = 0.f; s1_[r] = 0.f; }               \
    __builtin_amdgcn_s_setprio(1);                                             \
    _Pragma("unroll")                                                          \
    for (int dk = 0; dk < 4; ++dk) {                                           \
      half8 kf0 = *(const half8*)(lds + koff[dk] +                             \
                   ((CUR) * 32768 + (JT) * 8192));                             \
      s0_ = __builtin_amdgcn_mfma_f32_32x32x16_f16(kf0, qf[dk], s0_, 0, 0, 0); \
      half8 kf1 = *(const half8*)(lds + koff[dk] +                             \
                   ((CUR) * 32768 + (JT) * 8192 + 128));                       \
      s1_ = __builtin_amdgcn_mfma_f32_32x32x16_f16(kf1, qf[dk + 4], s1_, 0, 0, 0); \
    }                                                                          \
    __builtin_amdgcn_s_setprio(0);                                             \
    _Pragma("unroll")                                                          \
    for (int r = 0; r < 16; ++r) (S)[r] = s0_[r] + s1_[r];                     \
  } while (0)

#define TILE(CUR, T)                                                           \
  do {                                                                         \
    if ((T) + 1 < NT) STAGE((CUR) ^ 1, (T) + 1);                               \
    f32x16 sA, sB;                                                             \
    QK_HALF(sA, 0, CUR);                                                       \
    QK_HALF(sB, 1, CUR);                                                       \
    unsigned PA[4][2], PB[4][2];                                               \
    SM_HALF(sA, PA);                                                           \
    PV_HALF(PA, 0, CUR);                                                       \
    SM_HALF(sB, PB);                                                           \
    PV_HALF(PB, 2, CUR);                                                       \
    asm volatile("s_waitcnt vmcnt(0)");                                        \
    __syncthreads();                                                           \
  } while (0)

  STAGE(0, 0);
  asm volatile("s_waitcnt vmcnt(0)");
  __syncthreads();

  for (int t = 0; t < NT; t += 2) {
    TILE(0, t);
    TILE(1, t + 1);
  }
#undef TILE
#undef QK_HALF
#undef PV_HALF
#undef SM_HALF
#undef STAGE

  float lt = lsum + __shfl_xor(lsum, 32);
  const float rl = 1.0f / lt;
  const int qrow = q0 + w * 32 + l31;
  const int srow = hmap[qrow];
  _Float16* ob = att + (size_t)srow * HID + h * HD;
#pragma unroll
  for (int dt = 0; dt < 4; ++dt)
#pragma unroll
    for (int rq = 0; rq < 4; ++rq) {
      const int d0 = dt * 32 + 8 * rq + 4 * hib;
      half4 o;
      o[0] = (_Float16)(acc[dt][4 * rq + 0] * rl);
      o[1] = (_Float16)(acc[dt][4 * rq + 1] * rl);
      o[2] = (_Float16)(acc[dt][4 * rq + 2] * rl);
      o[3] = (_Float16)(acc[dt][4 * rq + 3] * rl);
      *(half4*)(ob + d0) = o;
    }
}

extern "C" void kernel_launch(void* const* d_in, const int* in_sizes, int n_in,
                              void* d_out, int out_size, void* d_ws, size_t ws_size,
                              hipStream_t stream)
{
  const float* x     = (const float*)d_in[0];
  const float* w_qkv = (const float*)d_in[1];
  const float* w_out = (const float*)d_in[2];
  const int*   hmap  = (const int*)d_in[3];
  float* out = (float*)d_out;

  char* ws = (char*)d_ws;
  int* gidx = (int*)ws;                                          ws += 8192;
  _Float16* x16    = (_Float16*)ws;  // aliased with att16 (x16 dead after QKV GEMM)
  _Float16* att16  = (_Float16*)ws;                              ws += (size_t)S_LEN * HID * 2;
  _Float16* wqkv16 = (_Float16*)ws;                              ws += (size_t)3 * HID * HID * 2;
  _Float16* wout16 = (_Float16*)ws;                              ws += (size_t)HID * HID * 2;
  _Float16* q16    = (_Float16*)ws;                              ws += (size_t)S_LEN * HID * 2;
  char* kimg  = ws;                                              ws += (size_t)NH * NT * 16384;
  char* vtimg = ws;

  k_build_idx<<<8, 256, 0, stream>>>(hmap, gidx);
  k_cvt_all<<<(NX8 + NW8 + NO8 + 255) / 256, 256, 0, stream>>>(x, w_qkv, w_out,
                                                               x16, wqkv16, wout16);

  // fused 8-phase 256^2: Q = x @ wq^T AND KV images = x[gidx] @ wkv^T
  k_gemm_qkv8<<<256, 512, 131072, stream>>>(x16, wqkv16, q16, gidx, kimg, vtimg);

  k_attn12<<<NH * (S_LEN / QBLK), 512, 65536, stream>>>(q16, kimg, vtimg, hmap, att16);

  // out = att @ w_out^T  (4096 x 2048, fp32)
  dim3 go(HID / 128, S_LEN / 128);
  k_gemm_out<<<go, 256, 0, stream>>>(att16, wout16, out, S_LEN, HID, HID);
}

// Round 20
// 209.051 us; speedup vs baseline: 1.0751x; 1.0333x over previous
//
#include <hip/hip_runtime.h>
#include <math.h>

#define S_LEN 4096
#define HID   2048
#define NH    16
#define HD    128
#define NKV   2048
#define KT    64
#define QBLK  256
#define NT    (NKV / KT)
// (1/sqrt(128)) * log2(e) -- folded into Q so QK^T lands in exp2 domain
#define QSCALE 0.12754103668587426f

typedef __attribute__((ext_vector_type(8))) _Float16 half8;
typedef __attribute__((ext_vector_type(4))) _Float16 half4;
typedef __attribute__((ext_vector_type(2))) __fp16 fp16x2;
typedef __attribute__((ext_vector_type(4))) float f32x4;
typedef __attribute__((ext_vector_type(16))) float f32x16;

#define GLB_AS __attribute__((address_space(1)))
#define LDS_AS __attribute__((address_space(3)))

#if __has_builtin(__builtin_amdgcn_exp2f)
#define EXP2(x) __builtin_amdgcn_exp2f(x)
#else
#define EXP2(x) exp2f(x)
#endif

__device__ __forceinline__ void gload16(const void* g, void* l) {
  __builtin_amdgcn_global_load_lds((GLB_AS const void*)g, (LDS_AS void*)l, 16, 0, 0);
}

__device__ __forceinline__ unsigned pkrtz(float a, float b) {
  union { fp16x2 h; unsigned u; } cv;
  cv.h = __builtin_amdgcn_cvt_pkrtz(a, b);
  return cv.u;
}

// ---------- fused fp32 -> fp16 conversion for x, w_qkv, w_out ----------
#define NX8  (S_LEN * HID / 8)
#define NW8  (3 * HID * HID / 8)
#define NO8  (HID * HID / 8)
__global__ void k_cvt_all(const float* __restrict__ x, const float* __restrict__ wq,
                          const float* __restrict__ wo, _Float16* __restrict__ x16,
                          _Float16* __restrict__ wq16, _Float16* __restrict__ wo16) {
  int i = blockIdx.x * 256 + threadIdx.x;
  const float* src; _Float16* dst; int j;
  if (i < NX8)            { src = x;  dst = x16;  j = i; }
  else if (i < NX8 + NW8) { src = wq; dst = wq16; j = i - NX8; }
  else                    { src = wo; dst = wo16; j = i - NX8 - NW8; }
  float4 a = ((const float4*)src)[2 * j];
  float4 b = ((const float4*)src)[2 * j + 1];
  half8 h;
  h[0] = (_Float16)a.x; h[1] = (_Float16)a.y; h[2] = (_Float16)a.z; h[3] = (_Float16)a.w;
  h[4] = (_Float16)b.x; h[5] = (_Float16)b.y; h[6] = (_Float16)b.z; h[7] = (_Float16)b.w;
  ((half8*)dst)[j] = h;
}

// ---------- 256x256 8-phase fused Q+KV GEMM (gidx folded: hmap[2*idx]) ----------
__global__ __launch_bounds__(512, 2)
void k_gemm_qkv8(const _Float16* __restrict__ A, const _Float16* __restrict__ wqkv,
                 _Float16* __restrict__ q16, const int* __restrict__ hmap,
                 char* __restrict__ kimg, char* __restrict__ vtimg)
{
  extern __shared__ __align__(16) char lds[];
  const int tid = threadIdx.x;
  const int w = tid >> 6, lane = tid & 63;
  const int l15 = lane & 15, l4 = lane >> 4;
  const int wr = w >> 2, wc = w & 3;
  const int K = HID;

  const int bid = (blockIdx.x & 7) * 32 + (blockIdx.x >> 3);  // XCD-chunked bijective
  const bool qpart = bid < 128;
  int m0, n0;
  const _Float16* B;
  if (qpart) { int b = bid;       m0 = (b >> 3) * 256; n0 = (b & 7) * 256;  B = wqkv; }
  else       { int b = bid - 128; m0 = (b >> 4) * 256; n0 = (b & 15) * 256; B = wqkv + (size_t)HID * HID; }

  const int r8 = lane >> 3;
  const int sl = (lane & 7) ^ r8;
  const _Float16* ApA[2][2];
  const _Float16* BpB[2][2];
#pragma unroll
  for (int mh = 0; mh < 2; ++mh)
#pragma unroll
    for (int L = 0; L < 2; ++L) {
      int rel = L * 128 + mh * 64 + w * 8 + r8;
      int grow = qpart ? (m0 + rel) : hmap[2 * (m0 + rel)];
      ApA[mh][L] = A + (size_t)grow * K + sl * 8;
    }
#pragma unroll
  for (int nh = 0; nh < 2; ++nh)
#pragma unroll
    for (int L = 0; L < 2; ++L) {
      int row = n0 + (L * 2 + (w >> 2)) * 64 + nh * 32 + (w & 3) * 8 + r8;
      BpB[nh][L] = B + (size_t)row * K + sl * 8;
    }

  const int sw0 = (l4 ^ (l15 & 7)) * 16;
  const int sw1 = ((4 + l4) ^ (l15 & 7)) * 16;
  const int rofs = l15 * 128;

  f32x4 acc[8][4];
#pragma unroll
  for (int i = 0; i < 8; ++i)
#pragma unroll
    for (int j = 0; j < 4; ++j) acc[i][j] = (f32x4){0.f, 0.f, 0.f, 0.f};
  half8 af[4][2], bf[2][2];

#define STG_A(MH, BUF, T)                                                       \
  do {                                                                          \
    gload16(ApA[MH][0] + (T) * 64, lds + (BUF)*65536 + (MH)*16384 + w * 1024);  \
    gload16(ApA[MH][1] + (T) * 64, lds + (BUF)*65536 + (MH)*16384 + 8192 + w * 1024); \
  } while (0)
#define STG_B(NH, BUF, T)                                                       \
  do {                                                                          \
    gload16(BpB[NH][0] + (T) * 64, lds + (BUF)*65536 + 32768 + (NH)*16384 + w * 1024); \
    gload16(BpB[NH][1] + (T) * 64, lds + (BUF)*65536 + 32768 + (NH)*16384 + 8192 + w * 1024); \
  } while (0)

#define PH(BUF, MH, NH, LA, LB, STG, WAITS)                                     \
  do {                                                                          \
    if (LA) {                                                                   \
      _Pragma("unroll")                                                         \
      for (int j = 0; j < 4; ++j) {                                             \
        af[j][0] = *(const half8*)(lds + (BUF)*65536 + (MH)*16384 + wr * 8192 + j * 2048 + rofs + sw0); \
        af[j][1] = *(const half8*)(lds + (BUF)*65536 + (MH)*16384 + wr * 8192 + j * 2048 + rofs + sw1); \
      }                                                                         \
    }                                                                           \
    if (LB) {                                                                   \
      _Pragma("unroll")                                                         \
      for (int jn = 0; jn < 2; ++jn) {                                          \
        bf[jn][0] = *(const half8*)(lds + (BUF)*65536 + 32768 + (NH)*16384 + wc * 4096 + jn * 2048 + rofs + sw0); \
        bf[jn][1] = *(const half8*)(lds + (BUF)*65536 + 32768 + (NH)*16384 + wc * 4096 + jn * 2048 + rofs + sw1); \
      }                                                                         \
    }                                                                           \
    STG;                                                                        \
    __builtin_amdgcn_s_barrier();                                               \
    __builtin_amdgcn_s_setprio(1);                                              \
    _Pragma("unroll")                                                           \
    for (int j = 0; j < 4; ++j)                                                 \
      _Pragma("unroll")                                                         \
      for (int jn = 0; jn < 2; ++jn)                                            \
        _Pragma("unroll")                                                       \
        for (int ks = 0; ks < 2; ++ks)                                          \
          acc[(MH)*4 + j][(NH)*2 + jn] = __builtin_amdgcn_mfma_f32_16x16x32_f16( \
              af[j][ks], bf[jn][ks], acc[(MH)*4 + j][(NH)*2 + jn], 0, 0, 0);    \
    __builtin_amdgcn_s_setprio(0);                                              \
    WAITS;                                                                      \
    __builtin_amdgcn_s_barrier();                                               \
  } while (0)

  STG_A(0, 0, 0); STG_B(1, 0, 0); STG_A(1, 0, 0); STG_B(0, 0, 0);
  STG_A(0, 1, 1); STG_B(1, 1, 1);
  asm volatile("s_waitcnt vmcnt(4)");
  __builtin_amdgcn_s_barrier();

  for (int i = 0; i < 15; ++i) {
    const int T1 = 2 * i + 1, T2 = 2 * i + 2, T3 = 2 * i + 3;
    PH(0, 0, 0, 1, 1, STG_A(1, 1, T1), (void)0);
    PH(0, 0, 1, 0, 1, STG_B(0, 1, T1), (void)0);
    PH(0, 1, 1, 1, 0, STG_A(0, 0, T2), (void)0);
    PH(0, 1, 0, 0, 1, STG_B(1, 0, T2), asm volatile("s_waitcnt vmcnt(4)"));
    PH(1, 0, 0, 1, 1, STG_A(1, 0, T2), (void)0);
    PH(1, 0, 1, 0, 1, STG_B(0, 0, T2), (void)0);
    PH(1, 1, 1, 1, 0, STG_A(0, 1, T3), (void)0);
    PH(1, 1, 0, 0, 1, STG_B(1, 1, T3), asm volatile("s_waitcnt vmcnt(4)"));
  }
  PH(0, 0, 0, 1, 1, STG_A(1, 1, 31), (void)0);
  PH(0, 0, 1, 0, 1, STG_B(0, 1, 31), (void)0);
  PH(0, 1, 1, 1, 0, (void)0, (void)0);
  PH(0, 1, 0, 0, 1, (void)0, asm volatile("s_waitcnt vmcnt(0)"));
  PH(1, 0, 0, 1, 1, (void)0, (void)0);
  PH(1, 0, 1, 0, 1, (void)0, (void)0);
  PH(1, 1, 1, 1, 0, (void)0, (void)0);
  PH(1, 1, 0, 0, 1, (void)0, (void)0);
#undef PH
#undef STG_A
#undef STG_B

#pragma unroll
  for (int mf = 0; mf < 8; ++mf)
#pragma unroll
    for (int nf = 0; nf < 4; ++nf)
#pragma unroll
      for (int e = 0; e < 4; ++e) {
        int row = m0 + wr * 128 + mf * 16 + l4 * 4 + e;
        int col = n0 + wc * 64 + nf * 16 + l15;
        _Float16 val = (_Float16)acc[mf][nf][e];
        if (qpart) {
          q16[(size_t)row * HID + col] = val;
        } else {
          int r = row;
          int t = r >> 6, j = r & 63;
          if (col < HID) {
            int h = col >> 7, d = col & 127;
            int off = (h * 32 + t) * 16384 + ((j * 256 + 2 * d) ^ ((j & 7) << 4));
            *(_Float16*)(kimg + off) = val;
          } else {
            int nn = col - HID;
            int h = nn >> 7, d = nn & 127;
            int off = (h * 32 + t) * 16384 + ((d * 128 + 2 * j) ^ ((d & 7) << 4));
            *(_Float16*)(vtimg + off) = val;
          }
        }
      }
}

// ---------- out GEMM (f32 C), 128^2 structure ----------
__global__ __launch_bounds__(256)
void k_gemm_out(const _Float16* __restrict__ A, const _Float16* __restrict__ B,
                float* __restrict__ C, int M, int N, int K)
{
  __shared__ __align__(16) char Asl[16384];
  __shared__ __align__(16) char Bsl[16384];
  const int tid = threadIdx.x;
  const int w = tid >> 6, lane = tid & 63;
  const int l15 = lane & 15, l4 = lane >> 4;
  const int m0 = blockIdx.y * 128, n0 = blockIdx.x * 128;
  const int wr = w >> 1, wc = w & 1;

  const int srow  = lane >> 3;
  const int kso   = ((lane & 7) ^ srow) * 8;
  const _Float16* Ap[4];
  const _Float16* Bp[4];
#pragma unroll
  for (int q = 0; q < 4; ++q) {
    int row = m0 + 32 * w + 8 * q + srow;
    Ap[q] = A + (size_t)row * K + kso;
    Bp[q] = B + (size_t)(n0 + 32 * w + 8 * q + srow) * K + kso;
  }

  f32x4 acc[4][4];
#pragma unroll
  for (int i = 0; i < 4; ++i)
#pragma unroll
    for (int j = 0; j < 4; ++j) acc[i][j] = (f32x4){0.f, 0.f, 0.f, 0.f};

#define STAGE_T(k0)                                                  \
  do {                                                               \
    _Pragma("unroll")                                                \
    for (int q = 0; q < 4; ++q) {                                    \
      gload16(Ap[q] + (k0), Asl + (4 * w + q) * 1024 + lane * 16);   \
      gload16(Bp[q] + (k0), Bsl + (4 * w + q) * 1024 + lane * 16);   \
    }                                                                \
  } while (0)

  STAGE_T(0);
  __syncthreads();

  const int nt = K >> 6;
  for (int t = 0; t < nt; ++t) {
    half8 af[4][2], bf[4][2];
#pragma unroll
    for (int mi = 0; mi < 4; ++mi) {
      int row = wr * 64 + mi * 16 + l15;
#pragma unroll
      for (int ks = 0; ks < 2; ++ks)
        af[mi][ks] = *(const half8*)(Asl + row * 128 + (((ks * 4 + l4) ^ (row & 7)) * 16));
    }
#pragma unroll
    for (int ni = 0; ni < 4; ++ni) {
      int row = wc * 64 + ni * 16 + l15;
#pragma unroll
      for (int ks = 0; ks < 2; ++ks)
        bf[ni][ks] = *(const half8*)(Bsl + row * 128 + (((ks * 4 + l4) ^ (row & 7)) * 16));
    }
    __syncthreads();
    if (t + 1 < nt) STAGE_T((t + 1) * 64);
    __builtin_amdgcn_s_setprio(1);
#pragma unroll
    for (int mi = 0; mi < 4; ++mi)
#pragma unroll
      for (int ni = 0; ni < 4; ++ni)
#pragma unroll
        for (int ks = 0; ks < 2; ++ks)
          acc[mi][ni] = __builtin_amdgcn_mfma_f32_16x16x32_f16(af[mi][ks], bf[ni][ks], acc[mi][ni], 0, 0, 0);
    __builtin_amdgcn_s_setprio(0);
    __syncthreads();
  }
#undef STAGE_T

  const int rbase = m0 + wr * 64 + l4 * 4;
  const int cbase = n0 + wc * 64 + l15;
#pragma unroll
  for (int mi = 0; mi < 4; ++mi)
#pragma unroll
    for (int ni = 0; ni < 4; ++ni)
#pragma unroll
      for (int e = 0; e < 4; ++e)
        C[(size_t)(rbase + mi * 16 + e) * N + cbase + ni * 16] = acc[mi][ni][e];
}

// ---------- 32x32 MFMA flash attention: half-tile pipeline (R17 exact) ----------
__global__ __launch_bounds__(512, 2)
void k_attn9(const _Float16* __restrict__ qmat, const char* __restrict__ kimg,
             const char* __restrict__ vtimg, const int* __restrict__ hmap,
             _Float16* __restrict__ att)
{
  extern __shared__ __align__(16) char lds[];
  const int tid = threadIdx.x;
  const int w = tid >> 6, lane = tid & 63;
  const int l31 = lane & 31;
  const bool hi = (lane >> 5) != 0;
  const int hib = hi ? 1 : 0;
  const int work = (blockIdx.x & 7) * 32 + (blockIdx.x >> 3);  // XCD-chunked, bijective
  const int h  = work >> 4;
  const int q0 = (work & 15) * QBLK;

  half8 qf[8];
  {
    const int qrow = q0 + w * 32 + l31;
    const _Float16* qb = qmat + (size_t)qrow * HID + h * HD + hib * 8;
    const _Float16 qs = (_Float16)QSCALE;
#pragma unroll
    for (int dk = 0; dk < 8; ++dk) {
      half8 v = *(const half8*)(qb + 16 * dk);
#pragma unroll
      for (int q = 0; q < 8; ++q) v[q] *= qs;
      qf[dk] = v;
    }
  }

  const int swz = (l31 & 7) << 4;
  int koff[4], voff[4];
#pragma unroll
  for (int i = 0; i < 4; ++i) {
    koff[i] = l31 * 256 + ((i * 32 + hib * 16) ^ swz);
    voff[i] = 16384 + l31 * 128 + ((i * 32 + hib * 16) ^ swz);
  }

  const char* kbase = kimg  + (size_t)h * NT * 16384;
  const char* vbase = vtimg + (size_t)h * NT * 16384;

  f32x16 acc[4];
#pragma unroll
  for (int dt = 0; dt < 4; ++dt)
#pragma unroll
    for (int r = 0; r < 16; ++r) acc[dt][r] = 0.f;
  float lsum = 0.f;

#define STAGE(buf, t)                                                          \
  do {                                                                         \
    const char* ks_ = kbase + (size_t)(t) * 16384;                             \
    const char* vs_ = vbase + (size_t)(t) * 16384;                             \
    char* d_ = lds + (buf) * 32768;                                            \
    gload16(ks_ + w * 1024 + lane * 16,          d_ + w * 1024);               \
    gload16(ks_ + (8 + w) * 1024 + lane * 16,    d_ + (8 + w) * 1024);         \
    gload16(vs_ + w * 1024 + lane * 16,          d_ + 16384 + w * 1024);       \
    gload16(vs_ + (8 + w) * 1024 + lane * 16,    d_ + 16384 + (8 + w) * 1024); \
  } while (0)

#define SM_HALF(S, PPK)                                                        \
  do {                                                                         \
    float p_[16];                                                              \
    _Pragma("unroll")                                                          \
    for (int r = 0; r < 16; ++r) { p_[r] = EXP2((S)[r]); lsum += p_[r]; }      \
    _Pragma("unroll")                                                          \
    for (int rq = 0; rq < 4; ++rq)                                             \
      _Pragma("unroll")                                                        \
      for (int h2 = 0; h2 < 2; ++h2)                                           \
        PPK[rq][h2] = pkrtz(p_[4 * rq + 2 * h2], p_[4 * rq + 2 * h2 + 1]);     \
  } while (0)

#define PV_HALF(PPK, KSB, CUR)                                                 \
  do {                                                                         \
    _Pragma("unroll")                                                          \
    for (int k1 = 0; k1 < 2; ++k1) {                                           \
      unsigned send0 = hi ? PPK[2 * k1][0]     : PPK[2 * k1 + 1][0];           \
      unsigned send1 = hi ? PPK[2 * k1][1]     : PPK[2 * k1 + 1][1];           \
      unsigned recv0 = (unsigned)__shfl_xor((int)send0, 32);                   \
      unsigned recv1 = (unsigned)__shfl_xor((int)send1, 32);                   \
      unsigned self0 = hi ? PPK[2 * k1 + 1][0] : PPK[2 * k1][0];               \
      unsigned self1 = hi ? PPK[2 * k1 + 1][1] : PPK[2 * k1][1];               \
      union { unsigned u[4]; half8 hv; } pf;                                   \
      pf.u[0] = hi ? recv0 : self0;                                            \
      pf.u[1] = hi ? recv1 : self1;                                            \
      pf.u[2] = hi ? self0 : recv0;                                            \
      pf.u[3] = hi ? self1 : recv1;                                            \
      __builtin_amdgcn_s_setprio(1);                                           \
      _Pragma("unroll")                                                        \
      for (int dt = 0; dt < 4; ++dt) {                                         \
        half8 vf = *(const half8*)(lds + voff[(KSB) + k1] +                    \
                    ((CUR) * 32768 + dt * 4096));                              \
        acc[dt] = __builtin_amdgcn_mfma_f32_32x32x16_f16(vf, pf.hv, acc[dt], 0, 0, 0); \
      }                                                                        \
      __builtin_amdgcn_s_setprio(0);                                           \
    }                                                                          \
  } while (0)

#define QK_HALF(S, JT, CUR)                                                    \
  do {                                                                         \
    _Pragma("unroll")                                                          \
    for (int r = 0; r < 16; ++r) (S)[r] = 0.f;                                 \
    __builtin_amdgcn_s_setprio(1);                                             \
    _Pragma("unroll")                                                          \
    for (int dk = 0; dk < 8; ++dk) {                                           \
      half8 kf = *(const half8*)(lds + koff[dk & 3] +                          \
                  ((CUR) * 32768 + (JT) * 8192 + (dk >> 2) * 128));            \
      (S) = __builtin_amdgcn_mfma_f32_32x32x16_f16(kf, qf[dk], (S), 0, 0, 0);  \
    }                                                                          \
    __builtin_amdgcn_s_setprio(0);                                             \
  } while (0)

#define TILE(CUR, T)                                                           \
  do {                                                                         \
    if ((T) + 1 < NT) STAGE((CUR) ^ 1, (T) + 1);                               \
    f32x16 sA, sB;                                                             \
    QK_HALF(sA, 0, CUR);                                                       \
    QK_HALF(sB, 1, CUR);                                                       \
    unsigned PA[4][2], PB[4][2];                                               \
    SM_HALF(sA, PA);                                                           \
    PV_HALF(PA, 0, CUR);                                                       \
    SM_HALF(sB, PB);                                                           \
    PV_HALF(PB, 2, CUR);                                                       \
    asm volatile("s_waitcnt vmcnt(0)");                                        \
    __syncthreads();                                                           \
  } while (0)

  STAGE(0, 0);
  asm volatile("s_waitcnt vmcnt(0)");
  __syncthreads();

  for (int t = 0; t < NT; t += 2) {
    TILE(0, t);
    TILE(1, t + 1);
  }
#undef TILE
#undef QK_HALF
#undef PV_HALF
#undef SM_HALF
#undef STAGE

  float lt = lsum + __shfl_xor(lsum, 32);
  const float rl = 1.0f / lt;
  const int qrow = q0 + w * 32 + l31;
  const int srow = hmap[qrow];
  _Float16* ob = att + (size_t)srow * HID + h * HD;
#pragma unroll
  for (int dt = 0; dt < 4; ++dt)
#pragma unroll
    for (int rq = 0; rq < 4; ++rq) {
      const int d0 = dt * 32 + 8 * rq + 4 * hib;
      half4 o;
      o[0] = (_Float16)(acc[dt][4 * rq + 0] * rl);
      o[1] = (_Float16)(acc[dt][4 * rq + 1] * rl);
      o[2] = (_Float16)(acc[dt][4 * rq + 2] * rl);
      o[3] = (_Float16)(acc[dt][4 * rq + 3] * rl);
      *(half4*)(ob + d0) = o;
    }
}

extern "C" void kernel_launch(void* const* d_in, const int* in_sizes, int n_in,
                              void* d_out, int out_size, void* d_ws, size_t ws_size,
                              hipStream_t stream)
{
  const float* x     = (const float*)d_in[0];
  const float* w_qkv = (const float*)d_in[1];
  const float* w_out = (const float*)d_in[2];
  const int*   hmap  = (const int*)d_in[3];
  float* out = (float*)d_out;

  char* ws = (char*)d_ws;
  _Float16* x16    = (_Float16*)ws;  // aliased with att16 (x16 dead after QKV GEMM)
  _Float16* att16  = (_Float16*)ws;                              ws += (size_t)S_LEN * HID * 2;
  _Float16* wqkv16 = (_Float16*)ws;                              ws += (size_t)3 * HID * HID * 2;
  _Float16* wout16 = (_Float16*)ws;                              ws += (size_t)HID * HID * 2;
  _Float16* q16    = (_Float16*)ws;                              ws += (size_t)S_LEN * HID * 2;
  char* kimg  = ws;                                              ws += (size_t)NH * NT * 16384;
  char* vtimg = ws;

  k_cvt_all<<<(NX8 + NW8 + NO8 + 255) / 256, 256, 0, stream>>>(x, w_qkv, w_out,
                                                               x16, wqkv16, wout16);

  // fused 8-phase 256^2: Q = x @ wq^T AND KV images = x[hmap[2i]] @ wkv^T
  k_gemm_qkv8<<<256, 512, 131072, stream>>>(x16, wqkv16, q16, hmap, kimg, vtimg);

  k_attn9<<<NH * (S_LEN / QBLK), 512, 65536, stream>>>(q16, kimg, vtimg, hmap, att16);

  // out = att @ w_out^T  (4096 x 2048, fp32)
  dim3 go(HID / 128, S_LEN / 128);
  k_gemm_out<<<go, 256, 0, stream>>>(att16, wout16, out, S_LEN, HID, HID);
}

// Round 21
// 208.037 us; speedup vs baseline: 1.0804x; 1.0049x over previous
//
#include <hip/hip_runtime.h>
#include <math.h>

#define S_LEN 4096
#define HID   2048
#define NH    16
#define HD    128
#define NKV   2048
#define KT    64
#define QBLK  256
#define NT    (NKV / KT)
// (1/sqrt(128)) * log2(e) -- folded into Q so QK^T lands in exp2 domain
#define QSCALE 0.12754103668587426f

typedef __attribute__((ext_vector_type(8))) _Float16 half8;
typedef __attribute__((ext_vector_type(4))) _Float16 half4;
typedef __attribute__((ext_vector_type(2))) __fp16 fp16x2;
typedef __attribute__((ext_vector_type(4))) float f32x4;
typedef __attribute__((ext_vector_type(16))) float f32x16;

#define GLB_AS __attribute__((address_space(1)))
#define LDS_AS __attribute__((address_space(3)))

#if __has_builtin(__builtin_amdgcn_exp2f)
#define EXP2(x) __builtin_amdgcn_exp2f(x)
#else
#define EXP2(x) exp2f(x)
#endif

__device__ __forceinline__ void gload16(const void* g, void* l) {
  __builtin_amdgcn_global_load_lds((GLB_AS const void*)g, (LDS_AS void*)l, 16, 0, 0);
}

__device__ __forceinline__ unsigned pkrtz(float a, float b) {
  union { fp16x2 h; unsigned u; } cv;
  cv.h = __builtin_amdgcn_cvt_pkrtz(a, b);
  return cv.u;
}

// ---------- fused fp32 -> fp16 conversion for x, w_qkv, w_out ----------
#define NX8  (S_LEN * HID / 8)
#define NW8  (3 * HID * HID / 8)
#define NO8  (HID * HID / 8)
__global__ void k_cvt_all(const float* __restrict__ x, const float* __restrict__ wq,
                          const float* __restrict__ wo, _Float16* __restrict__ x16,
                          _Float16* __restrict__ wq16, _Float16* __restrict__ wo16) {
  int i = blockIdx.x * 256 + threadIdx.x;
  const float* src; _Float16* dst; int j;
  if (i < NX8)            { src = x;  dst = x16;  j = i; }
  else if (i < NX8 + NW8) { src = wq; dst = wq16; j = i - NX8; }
  else                    { src = wo; dst = wo16; j = i - NX8 - NW8; }
  float4 a = ((const float4*)src)[2 * j];
  float4 b = ((const float4*)src)[2 * j + 1];
  half8 h;
  h[0] = (_Float16)a.x; h[1] = (_Float16)a.y; h[2] = (_Float16)a.z; h[3] = (_Float16)a.w;
  h[4] = (_Float16)b.x; h[5] = (_Float16)b.y; h[6] = (_Float16)b.z; h[7] = (_Float16)b.w;
  ((half8*)dst)[j] = h;
}

// ---------- 256x256 8-phase fused Q+KV GEMM (R17/R20, unchanged) ----------
__global__ __launch_bounds__(512, 2)
void k_gemm_qkv8(const _Float16* __restrict__ A, const _Float16* __restrict__ wqkv,
                 _Float16* __restrict__ q16, const int* __restrict__ hmap,
                 char* __restrict__ kimg, char* __restrict__ vtimg)
{
  extern __shared__ __align__(16) char lds[];
  const int tid = threadIdx.x;
  const int w = tid >> 6, lane = tid & 63;
  const int l15 = lane & 15, l4 = lane >> 4;
  const int wr = w >> 2, wc = w & 3;
  const int K = HID;

  const int bid = (blockIdx.x & 7) * 32 + (blockIdx.x >> 3);  // XCD-chunked bijective
  const bool qpart = bid < 128;
  int m0, n0;
  const _Float16* B;
  if (qpart) { int b = bid;       m0 = (b >> 3) * 256; n0 = (b & 7) * 256;  B = wqkv; }
  else       { int b = bid - 128; m0 = (b >> 4) * 256; n0 = (b & 15) * 256; B = wqkv + (size_t)HID * HID; }

  const int r8 = lane >> 3;
  const int sl = (lane & 7) ^ r8;
  const _Float16* ApA[2][2];
  const _Float16* BpB[2][2];
#pragma unroll
  for (int mh = 0; mh < 2; ++mh)
#pragma unroll
    for (int L = 0; L < 2; ++L) {
      int rel = L * 128 + mh * 64 + w * 8 + r8;
      int grow = qpart ? (m0 + rel) : hmap[2 * (m0 + rel)];
      ApA[mh][L] = A + (size_t)grow * K + sl * 8;
    }
#pragma unroll
  for (int nh = 0; nh < 2; ++nh)
#pragma unroll
    for (int L = 0; L < 2; ++L) {
      int row = n0 + (L * 2 + (w >> 2)) * 64 + nh * 32 + (w & 3) * 8 + r8;
      BpB[nh][L] = B + (size_t)row * K + sl * 8;
    }

  const int sw0 = (l4 ^ (l15 & 7)) * 16;
  const int sw1 = ((4 + l4) ^ (l15 & 7)) * 16;
  const int rofs = l15 * 128;

  f32x4 acc[8][4];
#pragma unroll
  for (int i = 0; i < 8; ++i)
#pragma unroll
    for (int j = 0; j < 4; ++j) acc[i][j] = (f32x4){0.f, 0.f, 0.f, 0.f};
  half8 af[4][2], bf[2][2];

#define STG_A(MH, BUF, T)                                                       \
  do {                                                                          \
    gload16(ApA[MH][0] + (T) * 64, lds + (BUF)*65536 + (MH)*16384 + w * 1024);  \
    gload16(ApA[MH][1] + (T) * 64, lds + (BUF)*65536 + (MH)*16384 + 8192 + w * 1024); \
  } while (0)
#define STG_B(NH, BUF, T)                                                       \
  do {                                                                          \
    gload16(BpB[NH][0] + (T) * 64, lds + (BUF)*65536 + 32768 + (NH)*16384 + w * 1024); \
    gload16(BpB[NH][1] + (T) * 64, lds + (BUF)*65536 + 32768 + (NH)*16384 + 8192 + w * 1024); \
  } while (0)

#define PH(BUF, MH, NH, LA, LB, STG, WAITS)                                     \
  do {                                                                          \
    if (LA) {                                                                   \
      _Pragma("unroll")                                                         \
      for (int j = 0; j < 4; ++j) {                                             \
        af[j][0] = *(const half8*)(lds + (BUF)*65536 + (MH)*16384 + wr * 8192 + j * 2048 + rofs + sw0); \
        af[j][1] = *(const half8*)(lds + (BUF)*65536 + (MH)*16384 + wr * 8192 + j * 2048 + rofs + sw1); \
      }                                                                         \
    }                                                                           \
    if (LB) {                                                                   \
      _Pragma("unroll")                                                         \
      for (int jn = 0; jn < 2; ++jn) {                                          \
        bf[jn][0] = *(const half8*)(lds + (BUF)*65536 + 32768 + (NH)*16384 + wc * 4096 + jn * 2048 + rofs + sw0); \
        bf[jn][1] = *(const half8*)(lds + (BUF)*65536 + 32768 + (NH)*16384 + wc * 4096 + jn * 2048 + rofs + sw1); \
      }                                                                         \
    }                                                                           \
    STG;                                                                        \
    __builtin_amdgcn_s_barrier();                                               \
    __builtin_amdgcn_s_setprio(1);                                              \
    _Pragma("unroll")                                                           \
    for (int j = 0; j < 4; ++j)                                                 \
      _Pragma("unroll")                                                         \
      for (int jn = 0; jn < 2; ++jn)                                            \
        _Pragma("unroll")                                                       \
        for (int ks = 0; ks < 2; ++ks)                                          \
          acc[(MH)*4 + j][(NH)*2 + jn] = __builtin_amdgcn_mfma_f32_16x16x32_f16( \
              af[j][ks], bf[jn][ks], acc[(MH)*4 + j][(NH)*2 + jn], 0, 0, 0);    \
    __builtin_amdgcn_s_setprio(0);                                              \
    WAITS;                                                                      \
    __builtin_amdgcn_s_barrier();                                               \
  } while (0)

  STG_A(0, 0, 0); STG_B(1, 0, 0); STG_A(1, 0, 0); STG_B(0, 0, 0);
  STG_A(0, 1, 1); STG_B(1, 1, 1);
  asm volatile("s_waitcnt vmcnt(4)");
  __builtin_amdgcn_s_barrier();

  for (int i = 0; i < 15; ++i) {
    const int T1 = 2 * i + 1, T2 = 2 * i + 2, T3 = 2 * i + 3;
    PH(0, 0, 0, 1, 1, STG_A(1, 1, T1), (void)0);
    PH(0, 0, 1, 0, 1, STG_B(0, 1, T1), (void)0);
    PH(0, 1, 1, 1, 0, STG_A(0, 0, T2), (void)0);
    PH(0, 1, 0, 0, 1, STG_B(1, 0, T2), asm volatile("s_waitcnt vmcnt(4)"));
    PH(1, 0, 0, 1, 1, STG_A(1, 0, T2), (void)0);
    PH(1, 0, 1, 0, 1, STG_B(0, 0, T2), (void)0);
    PH(1, 1, 1, 1, 0, STG_A(0, 1, T3), (void)0);
    PH(1, 1, 0, 0, 1, STG_B(1, 1, T3), asm volatile("s_waitcnt vmcnt(4)"));
  }
  PH(0, 0, 0, 1, 1, STG_A(1, 1, 31), (void)0);
  PH(0, 0, 1, 0, 1, STG_B(0, 1, 31), (void)0);
  PH(0, 1, 1, 1, 0, (void)0, (void)0);
  PH(0, 1, 0, 0, 1, (void)0, asm volatile("s_waitcnt vmcnt(0)"));
  PH(1, 0, 0, 1, 1, (void)0, (void)0);
  PH(1, 0, 1, 0, 1, (void)0, (void)0);
  PH(1, 1, 1, 1, 0, (void)0, (void)0);
  PH(1, 1, 0, 0, 1, (void)0, (void)0);
#undef PH
#undef STG_A
#undef STG_B

#pragma unroll
  for (int mf = 0; mf < 8; ++mf)
#pragma unroll
    for (int nf = 0; nf < 4; ++nf)
#pragma unroll
      for (int e = 0; e < 4; ++e) {
        int row = m0 + wr * 128 + mf * 16 + l4 * 4 + e;
        int col = n0 + wc * 64 + nf * 16 + l15;
        _Float16 val = (_Float16)acc[mf][nf][e];
        if (qpart) {
          q16[(size_t)row * HID + col] = val;
        } else {
          int r = row;
          int t = r >> 6, j = r & 63;
          if (col < HID) {
            int h = col >> 7, d = col & 127;
            int off = (h * 32 + t) * 16384 + ((j * 256 + 2 * d) ^ ((j & 7) << 4));
            *(_Float16*)(kimg + off) = val;
          } else {
            int nn = col - HID;
            int h = nn >> 7, d = nn & 127;
            int off = (h * 32 + t) * 16384 + ((d * 128 + 2 * j) ^ ((d & 7) << 4));
            *(_Float16*)(vtimg + off) = val;
          }
        }
      }
}

// ---------- 256x128-tile 8-phase out GEMM (f32 C) ----------
// 256 blocks (16x16) = 1/CU, 512 threads = 8 waves (2M x 4N; per-wave 128x32).
// LDS 96KB = 2 buf x (A 32KB + B 16KB), BK=64. A-halves: 2 gload16; B-halves:
// 1 gload16 (B-half nh holds rows wc*32+nh*16+[0,16) per wave-col chunk).
// Counted waits: vmcnt(3) at ph4/ph8 (= ph's own + previous phase's loads).
__global__ __launch_bounds__(512, 2)
void k_gemm_out8(const _Float16* __restrict__ A, const _Float16* __restrict__ B,
                 float* __restrict__ C)
{
  extern __shared__ __align__(16) char lds[];
  const int tid = threadIdx.x;
  const int w = tid >> 6, lane = tid & 63;
  const int l15 = lane & 15, l4 = lane >> 4;
  const int wr = w >> 2, wc = w & 3;
  const int K = HID;

  const int bid = (blockIdx.x & 7) * 32 + (blockIdx.x >> 3);  // XCD-chunked bijective
  const int m0 = (bid >> 4) * 256;
  const int n0 = (bid & 15) * 128;

  const int r8 = lane >> 3;
  const int sl = (lane & 7) ^ r8;
  const _Float16* ApA[2][2];
  const _Float16* Bp[2];
#pragma unroll
  for (int mh = 0; mh < 2; ++mh)
#pragma unroll
    for (int L = 0; L < 2; ++L) {
      int rel = L * 128 + mh * 64 + w * 8 + r8;
      ApA[mh][L] = A + (size_t)(m0 + rel) * K + sl * 8;
    }
#pragma unroll
  for (int nh = 0; nh < 2; ++nh) {
    int row = n0 + (w >> 1) * 32 + nh * 16 + (w & 1) * 8 + r8;
    Bp[nh] = B + (size_t)row * K + sl * 8;
  }

  const int sw0 = (l4 ^ (l15 & 7)) * 16;
  const int sw1 = ((4 + l4) ^ (l15 & 7)) * 16;
  const int rofs = l15 * 128;

  f32x4 acc[8][2];
#pragma unroll
  for (int i = 0; i < 8; ++i)
#pragma unroll
    for (int j = 0; j < 2; ++j) acc[i][j] = (f32x4){0.f, 0.f, 0.f, 0.f};
  half8 af[4][2], bf[2];

#define STG_A(MH, BUF, T)                                                       \
  do {                                                                          \
    gload16(ApA[MH][0] + (T) * 64, lds + (BUF)*49152 + (MH)*16384 + w * 1024);  \
    gload16(ApA[MH][1] + (T) * 64, lds + (BUF)*49152 + (MH)*16384 + 8192 + w * 1024); \
  } while (0)
#define STG_B(NH, BUF, T)                                                       \
  gload16(Bp[NH] + (T) * 64, lds + (BUF)*49152 + 32768 + (NH)*8192 + w * 1024)

#define PH(BUF, MH, NH, LA, STG, WAITS)                                         \
  do {                                                                          \
    if (LA) {                                                                   \
      _Pragma("unroll")                                                         \
      for (int j = 0; j < 4; ++j) {                                             \
        af[j][0] = *(const half8*)(lds + (BUF)*49152 + (MH)*16384 + wr * 8192 + j * 2048 + rofs + sw0); \
        af[j][1] = *(const half8*)(lds + (BUF)*49152 + (MH)*16384 + wr * 8192 + j * 2048 + rofs + sw1); \
      }                                                                         \
    }                                                                           \
    bf[0] = *(const half8*)(lds + (BUF)*49152 + 32768 + (NH)*8192 + wc * 2048 + rofs + sw0); \
    bf[1] = *(const half8*)(lds + (BUF)*49152 + 32768 + (NH)*8192 + wc * 2048 + rofs + sw1); \
    STG;                                                                        \
    __builtin_amdgcn_s_barrier();                                               \
    __builtin_amdgcn_s_setprio(1);                                              \
    _Pragma("unroll")                                                           \
    for (int j = 0; j < 4; ++j)                                                 \
      _Pragma("unroll")                                                         \
      for (int ks = 0; ks < 2; ++ks)                                            \
        acc[(MH)*4 + j][NH] = __builtin_amdgcn_mfma_f32_16x16x32_f16(           \
            af[j][ks], bf[ks], acc[(MH)*4 + j][NH], 0, 0, 0);                   \
    __builtin_amdgcn_s_setprio(0);                                              \
    WAITS;                                                                      \
    __builtin_amdgcn_s_barrier();                                               \
  } while (0)

  // prologue: buf0 {A0,B1,A1,B0} of tile 0 (6 loads), buf1 {A0,B1} of tile 1 (3)
  STG_A(0, 0, 0); STG_B(1, 0, 0); STG_A(1, 0, 0); STG_B(0, 0, 0);
  STG_A(0, 1, 1); STG_B(1, 1, 1);
  asm volatile("s_waitcnt vmcnt(3)");
  __builtin_amdgcn_s_barrier();

  for (int i = 0; i < 15; ++i) {
    const int T1 = 2 * i + 1, T2 = 2 * i + 2, T3 = 2 * i + 3;
    PH(0, 0, 0, 1, STG_A(1, 1, T1), (void)0);
    PH(0, 0, 1, 0, STG_B(0, 1, T1), (void)0);
    PH(0, 1, 1, 1, STG_A(0, 0, T2), (void)0);
    PH(0, 1, 0, 0, STG_B(1, 0, T2), asm volatile("s_waitcnt vmcnt(3)"));
    PH(1, 0, 0, 1, STG_A(1, 0, T2), (void)0);
    PH(1, 0, 1, 0, STG_B(0, 0, T2), (void)0);
    PH(1, 1, 1, 1, STG_A(0, 1, T3), (void)0);
    PH(1, 1, 0, 0, STG_B(1, 1, T3), asm volatile("s_waitcnt vmcnt(3)"));
  }
  PH(0, 0, 0, 1, STG_A(1, 1, 31), (void)0);
  PH(0, 0, 1, 0, STG_B(0, 1, 31), (void)0);
  PH(0, 1, 1, 1, (void)0, (void)0);
  PH(0, 1, 0, 0, (void)0, asm volatile("s_waitcnt vmcnt(0)"));
  PH(1, 0, 0, 1, (void)0, (void)0);
  PH(1, 0, 1, 0, (void)0, (void)0);
  PH(1, 1, 1, 1, (void)0, (void)0);
  PH(1, 1, 0, 0, (void)0, (void)0);
#undef PH
#undef STG_A
#undef STG_B

  // epilogue: wave (wr,wc) owns rows m0+wr*128..+128, cols n0+wc*32..+32
#pragma unroll
  for (int mf = 0; mf < 8; ++mf)
#pragma unroll
    for (int nf = 0; nf < 2; ++nf)
#pragma unroll
      for (int e = 0; e < 4; ++e) {
        int row = m0 + wr * 128 + mf * 16 + l4 * 4 + e;
        int col = n0 + wc * 32 + nf * 16 + l15;
        C[(size_t)row * HID + col] = acc[mf][nf][e];
      }
}

// ---------- 32x32 MFMA flash attention: half-tile pipeline (R17 exact) ----------
__global__ __launch_bounds__(512, 2)
void k_attn9(const _Float16* __restrict__ qmat, const char* __restrict__ kimg,
             const char* __restrict__ vtimg, const int* __restrict__ hmap,
             _Float16* __restrict__ att)
{
  extern __shared__ __align__(16) char lds[];
  const int tid = threadIdx.x;
  const int w = tid >> 6, lane = tid & 63;
  const int l31 = lane & 31;
  const bool hi = (lane >> 5) != 0;
  const int hib = hi ? 1 : 0;
  const int work = (blockIdx.x & 7) * 32 + (blockIdx.x >> 3);  // XCD-chunked, bijective
  const int h  = work >> 4;
  const int q0 = (work & 15) * QBLK;

  half8 qf[8];
  {
    const int qrow = q0 + w * 32 + l31;
    const _Float16* qb = qmat + (size_t)qrow * HID + h * HD + hib * 8;
    const _Float16 qs = (_Float16)QSCALE;
#pragma unroll
    for (int dk = 0; dk < 8; ++dk) {
      half8 v = *(const half8*)(qb + 16 * dk);
#pragma unroll
      for (int q = 0; q < 8; ++q) v[q] *= qs;
      qf[dk] = v;
    }
  }

  const int swz = (l31 & 7) << 4;
  int koff[4], voff[4];
#pragma unroll
  for (int i = 0; i < 4; ++i) {
    koff[i] = l31 * 256 + ((i * 32 + hib * 16) ^ swz);
    voff[i] = 16384 + l31 * 128 + ((i * 32 + hib * 16) ^ swz);
  }

  const char* kbase = kimg  + (size_t)h * NT * 16384;
  const char* vbase = vtimg + (size_t)h * NT * 16384;

  f32x16 acc[4];
#pragma unroll
  for (int dt = 0; dt < 4; ++dt)
#pragma unroll
    for (int r = 0; r < 16; ++r) acc[dt][r] = 0.f;
  float lsum = 0.f;

#define STAGE(buf, t)                                                          \
  do {                                                                         \
    const char* ks_ = kbase + (size_t)(t) * 16384;                             \
    const char* vs_ = vbase + (size_t)(t) * 16384;                             \
    char* d_ = lds + (buf) * 32768;                                            \
    gload16(ks_ + w * 1024 + lane * 16,          d_ + w * 1024);               \
    gload16(ks_ + (8 + w) * 1024 + lane * 16,    d_ + (8 + w) * 1024);         \
    gload16(vs_ + w * 1024 + lane * 16,          d_ + 16384 + w * 1024);       \
    gload16(vs_ + (8 + w) * 1024 + lane * 16,    d_ + 16384 + (8 + w) * 1024); \
  } while (0)

#define SM_HALF(S, PPK)                                                        \
  do {                                                                         \
    float p_[16];                                                              \
    _Pragma("unroll")                                                          \
    for (int r = 0; r < 16; ++r) { p_[r] = EXP2((S)[r]); lsum += p_[r]; }      \
    _Pragma("unroll")                                                          \
    for (int rq = 0; rq < 4; ++rq)                                             \
      _Pragma("unroll")                                                        \
      for (int h2 = 0; h2 < 2; ++h2)                                           \
        PPK[rq][h2] = pkrtz(p_[4 * rq + 2 * h2], p_[4 * rq + 2 * h2 + 1]);     \
  } while (0)

#define PV_HALF(PPK, KSB, CUR)                                                 \
  do {                                                                         \
    _Pragma("unroll")                                                          \
    for (int k1 = 0; k1 < 2; ++k1) {                                           \
      unsigned send0 = hi ? PPK[2 * k1][0]     : PPK[2 * k1 + 1][0];           \
      unsigned send1 = hi ? PPK[2 * k1][1]     : PPK[2 * k1 + 1][1];           \
      unsigned recv0 = (unsigned)__shfl_xor((int)send0, 32);                   \
      unsigned recv1 = (unsigned)__shfl_xor((int)send1, 32);                   \
      unsigned self0 = hi ? PPK[2 * k1 + 1][0] : PPK[2 * k1][0];               \
      unsigned self1 = hi ? PPK[2 * k1 + 1][1] : PPK[2 * k1][1];               \
      union { unsigned u[4]; half8 hv; } pf;                                   \
      pf.u[0] = hi ? recv0 : self0;                                            \
      pf.u[1] = hi ? recv1 : self1;                                            \
      pf.u[2] = hi ? self0 : recv0;                                            \
      pf.u[3] = hi ? self1 : recv1;                                            \
      __builtin_amdgcn_s_setprio(1);                                           \
      _Pragma("unroll")                                                        \
      for (int dt = 0; dt < 4; ++dt) {                                         \
        half8 vf = *(const half8*)(lds + voff[(KSB) + k1] +                    \
                    ((CUR) * 32768 + dt * 4096));                              \
        acc[dt] = __builtin_amdgcn_mfma_f32_32x32x16_f16(vf, pf.hv, acc[dt], 0, 0, 0); \
      }                                                                        \
      __builtin_amdgcn_s_setprio(0);                                           \
    }                                                                          \
  } while (0)

#define QK_HALF(S, JT, CUR)                                                    \
  do {                                                                         \
    _Pragma("unroll")                                                          \
    for (int r = 0; r < 16; ++r) (S)[r] = 0.f;                                 \
    __builtin_amdgcn_s_setprio(1);                                             \
    _Pragma("unroll")                                                          \
    for (int dk = 0; dk < 8; ++dk) {                                           \
      half8 kf = *(const half8*)(lds + koff[dk & 3] +                          \
                  ((CUR) * 32768 + (JT) * 8192 + (dk >> 2) * 128));            \
      (S) = __builtin_amdgcn_mfma_f32_32x32x16_f16(kf, qf[dk], (S), 0, 0, 0);  \
    }                                                                          \
    __builtin_amdgcn_s_setprio(0);                                             \
  } while (0)

#define TILE(CUR, T)                                                           \
  do {                                                                         \
    if ((T) + 1 < NT) STAGE((CUR) ^ 1, (T) + 1);                               \
    f32x16 sA, sB;                                                             \
    QK_HALF(sA, 0, CUR);                                                       \
    QK_HALF(sB, 1, CUR);                                                       \
    unsigned PA[4][2], PB[4][2];                                               \
    SM_HALF(sA, PA);                                                           \
    PV_HALF(PA, 0, CUR);                                                       \
    SM_HALF(sB, PB);                                                           \
    PV_HALF(PB, 2, CUR);                                                       \
    asm volatile("s_waitcnt vmcnt(0)");                                        \
    __syncthreads();                                                           \
  } while (0)

  STAGE(0, 0);
  asm volatile("s_waitcnt vmcnt(0)");
  __syncthreads();

  for (int t = 0; t < NT; t += 2) {
    TILE(0, t);
    TILE(1, t + 1);
  }
#undef TILE
#undef QK_HALF
#undef PV_HALF
#undef SM_HALF
#undef STAGE

  float lt = lsum + __shfl_xor(lsum, 32);
  const float rl = 1.0f / lt;
  const int qrow = q0 + w * 32 + l31;
  const int srow = hmap[qrow];
  _Float16* ob = att + (size_t)srow * HID + h * HD;
#pragma unroll
  for (int dt = 0; dt < 4; ++dt)
#pragma unroll
    for (int rq = 0; rq < 4; ++rq) {
      const int d0 = dt * 32 + 8 * rq + 4 * hib;
      half4 o;
      o[0] = (_Float16)(acc[dt][4 * rq + 0] * rl);
      o[1] = (_Float16)(acc[dt][4 * rq + 1] * rl);
      o[2] = (_Float16)(acc[dt][4 * rq + 2] * rl);
      o[3] = (_Float16)(acc[dt][4 * rq + 3] * rl);
      *(half4*)(ob + d0) = o;
    }
}

extern "C" void kernel_launch(void* const* d_in, const int* in_sizes, int n_in,
                              void* d_out, int out_size, void* d_ws, size_t ws_size,
                              hipStream_t stream)
{
  const float* x     = (const float*)d_in[0];
  const float* w_qkv = (const float*)d_in[1];
  const float* w_out = (const float*)d_in[2];
  const int*   hmap  = (const int*)d_in[3];
  float* out = (float*)d_out;

  char* ws = (char*)d_ws;
  _Float16* x16    = (_Float16*)ws;  // aliased with att16 (x16 dead after QKV GEMM)
  _Float16* att16  = (_Float16*)ws;                              ws += (size_t)S_LEN * HID * 2;
  _Float16* wqkv16 = (_Float16*)ws;                              ws += (size_t)3 * HID * HID * 2;
  _Float16* wout16 = (_Float16*)ws;                              ws += (size_t)HID * HID * 2;
  _Float16* q16    = (_Float16*)ws;                              ws += (size_t)S_LEN * HID * 2;
  char* kimg  = ws;                                              ws += (size_t)NH * NT * 16384;
  char* vtimg = ws;

  k_cvt_all<<<(NX8 + NW8 + NO8 + 255) / 256, 256, 0, stream>>>(x, w_qkv, w_out,
                                                               x16, wqkv16, wout16);

  // fused 8-phase 256^2: Q = x @ wq^T AND KV images = x[hmap[2i]] @ wkv^T
  k_gemm_qkv8<<<256, 512, 131072, stream>>>(x16, wqkv16, q16, hmap, kimg, vtimg);

  k_attn9<<<NH * (S_LEN / QBLK), 512, 65536, stream>>>(q16, kimg, vtimg, hmap, att16);

  // out = att @ w_out^T  (4096 x 2048, fp32), 8-phase 256x128 tiles
  k_gemm_out8<<<256, 512, 98304, stream>>>(att16, wout16, out);
}